// Round 10
// baseline (991.310 us; speedup 1.0000x reference)
//
#include <hip/hip_runtime.h>
#include <stdint.h>

#define NB 8
#define NN 2048
#define NU 256
#define CAP 64
#define BNEPS 0.001f
#define GSTR ((size_t)(NN * NU + 256))   // G mat stride in floats (256-float zero gap BEFORE each mat)

typedef __attribute__((ext_vector_type(8))) short short8;
typedef __attribute__((ext_vector_type(4))) float floatx4;
typedef unsigned short u16;
typedef unsigned int u32;

__device__ __forceinline__ float bf2f(u16 u) {
  union { u32 i; float f; } c; c.i = ((u32)u) << 16; return c.f;
}
__device__ __forceinline__ u16 f2bf(float f) {
  union { float f; u32 i; } c; c.f = f;
  return (u16)((c.i + 0x7fffu + ((c.i >> 16) & 1u)) >> 16);
}
// bf16 hi/lo split: a = bf2f(h) + bf2f(l) + O(2^-18 |a|)
__device__ __forceinline__ void splitbf(float a, u16& h, u16& l) {
  h = f2bf(a);
  l = f2bf(a - bf2f(h));
}

enum : unsigned {
  F_BIAS = 2u, F_SILU = 4u, F_MASKPRE = 8u, F_MASKPOST = 16u,
  F_ADDX = 32u, F_BN = 64u, F_ADDT = 128u, F_BPERMAT = 512u,
  F_TPLANES = 1024u, F_OUTHL = 2048u, F_GSTRIDE = 8192u
};

#define TP_MAT 524288   // per-batch transposed plane: 256 cols x 2048 rows (u16)
#define TP_LO  4194304  // transposed lo plane offset (u16 elems)
#define MSZ ((size_t)NN * NU)

struct WPtrs { const float* p[16]; };

// ---------------------------------------------------------------------------
// Merged prologue: [0,512) weight conv, [512,4608) x conv, [4608,20992) nbr
// (pads idx rows to CAP with -1), [20992,21040) zero the G mat gaps.
// ---------------------------------------------------------------------------
__global__ __launch_bounds__(256) void prologue_k(
    WPtrs wp, u16* __restrict__ wdst,
    const float* __restrict__ x, u16* __restrict__ xdst, size_t xLo,
    const float* __restrict__ adj, int* __restrict__ cnt, int* __restrict__ idx,
    float* __restrict__ ga, float* __restrict__ gb)
{
  int bid = blockIdx.x;
  int tid = threadIdx.x;
  __shared__ int c0;
  if (bid < 512) {
    // weight conversion: f32 [K=256][N=256] -> TWO bf16 swizzled-B^T planes
    int gid = bid * 256 + tid;  // 16 mats * 8192 chunks
    int mat = gid >> 13;
    int rem = gid & 8191;
    int kb = rem >> 10;
    int n = (rem >> 2) & 255;
    int slot = rem & 3;
    int qv = (slot - (n >> 1)) & 3;
    int k0 = kb * 32 + qv * 8;
    const float* W = wp.p[mat];
    u32 oh[4], ol[4];
#pragma unroll
    for (int t2 = 0; t2 < 4; t2++) {
      float f0 = W[(size_t)(k0 + 2 * t2) * 256 + n];
      float f1 = W[(size_t)(k0 + 2 * t2 + 1) * 256 + n];
      u16 h0, l0, h1, l1;
      splitbf(f0, h0, l0);
      splitbf(f1, h1, l1);
      oh[t2] = (u32)h0 | ((u32)h1 << 16);
      ol[t2] = (u32)l0 | ((u32)l1 << 16);
    }
    uint4 qh; qh.x = oh[0]; qh.y = oh[1]; qh.z = oh[2]; qh.w = oh[3];
    uint4 ql; ql.x = ol[0]; ql.y = ol[1]; ql.z = ol[2]; ql.w = ol[3];
    *(uint4*)(wdst + (size_t)gid * 8) = qh;
    *(uint4*)(wdst + 1048576 + (size_t)gid * 8) = ql;
  } else if (bid < 4608) {
    // x conversion: fp32 -> row-major hi/lo bf16 planes
    size_t i = ((size_t)(bid - 512) * 256 + tid) * 4;
    float4 v = *(const float4*)(x + i);
    u16 h0, l0, h1, l1, h2, l2, h3, l3;
    splitbf(v.x, h0, l0); splitbf(v.y, h1, l1);
    splitbf(v.z, h2, l2); splitbf(v.w, h3, l3);
    uint2 H; H.x = (u32)h0 | ((u32)h1 << 16); H.y = (u32)h2 | ((u32)h3 << 16);
    uint2 L; L.x = (u32)l0 | ((u32)l1 << 16); L.y = (u32)l2 | ((u32)l3 << 16);
    *(uint2*)(xdst + i) = H;
    *(uint2*)(xdst + xLo + i) = L;
  } else if (bid < 20992) {
    // neighbor-list build: one block per (b,m) row of adj; values exactly 0/1
    int row = bid - 4608;
    const float* base = adj + (size_t)row * NN;
    if (tid == 0) c0 = 0;
    __syncthreads();
#pragma unroll
    for (int j = 0; j < 8; j++) {
      int n = j * 256 + tid;  // coalesced
      if (base[n] != 0.f) {
        int p = atomicAdd(&c0, 1);
        if (p < CAP) idx[(size_t)row * CAP + p] = n;
      }
    }
    __syncthreads();
    int cc = (c0 < CAP ? c0 : CAP);
    // pad to CAP with sentinel -1 (points at the zero gap before each G mat)
    for (int p = cc + tid; p < CAP; p += 256) idx[(size_t)row * CAP + p] = -1;
    if (tid == 0) cnt[row] = cc;
  } else {
    // zero the 256-float gap before each of the 24 mats in GA and GB
    int g = bid - 20992;           // 0..47
    float* base = (g < 24 ? ga : gb) + (size_t)(g % 24) * GSTR;
    base[tid] = 0.f;
  }
}

// ---------------------------------------------------------------------------
// Per-chain epilogue (compile-time flags). Wave layout: 32 rows x 32 cols
// (mt=2 row tiles, nt=2 col tiles), wave w owns cols [w*32, w*32+32).
// (The F_GSTRIDE G-output path is handled inline in gemm_k with LDS-staged
//  full-line nontemporal writes, not here.)
// ---------------------------------------------------------------------------
template <unsigned F>
__device__ __forceinline__ void gemm_epi(
    floatx4 (&acc)[2][2], int b, int bm, int w, int m16, int q,
    const float* __restrict__ bias, const float* __restrict__ mask,
    const float* __restrict__ xf32,
    const float* __restrict__ gma, const float* __restrict__ bta,
    const float* __restrict__ bmu, const float* __restrict__ bvr,
    const float* __restrict__ addt, void* __restrict__ outp, size_t oLo)
{
#pragma unroll
  for (int mt = 0; mt < 2; mt++) {
    if (F & F_TPLANES) {
      u16* oh = (u16*)outp + (size_t)b * TP_MAT;
      u16* ol = oh + TP_LO;
      int gr0 = bm + mt * 16 + q * 4;
#pragma unroll
      for (int nt = 0; nt < 2; nt++) {
        int col = w * 32 + nt * 16 + m16;
        u16 hh[4], ll[4];
#pragma unroll
        for (int r = 0; r < 4; r++) {
          float t2 = acc[mt][nt][r];
          float mv = mask[b * NN + gr0 + r];
          if (F & F_MASKPRE) t2 *= mv;
          if (F & F_SILU) t2 = t2 / (1.f + __expf(-t2));
          if (F & F_MASKPOST) t2 *= mv;
          splitbf(t2, hh[r], ll[r]);
        }
        uint2 H2, L2v;
        H2.x = (u32)hh[0] | ((u32)hh[1] << 16);
        H2.y = (u32)hh[2] | ((u32)hh[3] << 16);
        L2v.x = (u32)ll[0] | ((u32)ll[1] << 16);
        L2v.y = (u32)ll[2] | ((u32)ll[3] << 16);
        *(uint2*)(oh + (size_t)col * 2048 + gr0) = H2;
        *(uint2*)(ol + (size_t)col * 2048 + gr0) = L2v;
      }
    } else {
#pragma unroll
      for (int r = 0; r < 4; r++) {
        int gr = bm + mt * 16 + q * 4 + r;
        float mval = 1.f;
        if (F & (F_MASKPRE | F_MASKPOST)) mval = mask[b * NN + gr];
#pragma unroll
        for (int nt = 0; nt < 2; nt++) {
          int col = w * 32 + nt * 16 + m16;
          float t2 = acc[mt][nt][r];
          if (F & F_BIAS) t2 += bias[col];
          if (F & F_MASKPRE) t2 *= mval;
          if (F & F_SILU) t2 = t2 / (1.f + __expf(-t2));
          if (F & F_ADDX) t2 += xf32[((size_t)b * NN + gr) * NU + col];
          if (F & F_BN) t2 = gma[col] * (t2 - bmu[col]) * rsqrtf(bvr[col] + BNEPS) + bta[col];
          if (F & F_ADDT) t2 += addt[((size_t)b * NN + gr) * NU + col];
          if (F & F_MASKPOST) t2 *= mval;
          size_t o = ((size_t)b * NN + gr) * NU + col;
          if (F & F_OUTHL) {
            u16 h0, l0;
            splitbf(t2, h0, l0);
            ((u16*)outp)[o] = h0;
            ((u16*)outp)[o + oLo] = l0;
          } else {
            ((float*)outp)[o] = t2;
          }
        }
      }
    }
  }
}

// ---------------------------------------------------------------------------
// Dense GEMM, fp32-emulated via bf16 hi/lo 3-term MFMA. Up to 3 fused chains.
// Tile 32 rows x 256 cols, 512 thr = 8 waves, each 32x32 (B unique per wave).
// LDS 33.8 KB -> 4 blocks/CU = 32 waves/CU.
// A-staging modes (compile-time SF):
//   SF == 0 : A pre-split hi/lo planes, pure-copy staged to LDS.
//   SF != 0 : FUSED AGGREGATION staging — A-tile computed on the fly as
//             silu( sum_{n in nbr(row)} gsrc[b][n][:] + sbias ) [*mask],
//             split hi/lo directly into LDS. 4 rows/wave, branchy interleaved
//             exact gather (best measured variant, R2).
// F_GSTRIDE output (G mats): after the K-loop the A LDS buffers are dead, so
//   the C-tile is staged there and written with FULL-CACHE-LINE nontemporal
//   stores (512 thr x 64B coalesced). Rationale: G-out dirty lines in L2
//   (write-allocate) evict the 16x-reused G-in rows; NT full-line writes
//   avoid pollution without the partial-line write amplification R3 hit.
// DK : dual-K mode (NG==1): after chain-0 K-loop, acc = silu(acc + b1[col]),
//      restage A from A1, second K-loop with W1 accumulating.
// B: per-lane fragments straight from swizzled global planes (L2-hot).
// Grid 1-D, xcd = id&7. NG==3 grid 1536, chain-major (t>>6), 64 tiles/chain.
// NOTE: cross-dispatch L2 reuse is impossible (agent-scope release/acquire at
// dispatch boundaries + non-coherent per-XCD L2s) — R5/R6 chain-split lesson.
// ---------------------------------------------------------------------------
template <int NG, unsigned SF, unsigned F0, unsigned F1, unsigned F2, bool DK = false>
__global__ __launch_bounds__(512, 8) void gemm_k(
    const u16* __restrict__ A0, const u16* __restrict__ A1, const u16* __restrict__ A2,
    size_t aLo,
    const u16* __restrict__ W0, const u16* __restrict__ W1, const u16* __restrict__ W2,
    size_t wLo,
    const float* __restrict__ b0, const float* __restrict__ b1, const float* __restrict__ b2,
    const float* __restrict__ mask,
    const float* __restrict__ xf32,
    const float* __restrict__ gma, const float* __restrict__ bta,
    const float* __restrict__ bmu, const float* __restrict__ bvr,
    const float* __restrict__ addt,
    void* __restrict__ o0, void* __restrict__ o1, void* __restrict__ o2,
    size_t oLo,
    const float* __restrict__ gsrc,
    const float* __restrict__ sb0, const float* __restrict__ sb1, const float* __restrict__ sb2,
    const int* __restrict__ ncnt, const int* __restrict__ nidx)
{
  const int tid = threadIdx.x;
  const int id = blockIdx.x;
  const int xcd = id & 7;
  const int t = id >> 3;
  const int chain = (NG == 1) ? 0 : (t >> 6);   // chain-major: 64 tiles/chain
  const int xt = (NG == 1) ? t : (t & 63);
  const int b = xcd;
  const int bm = xt * 32;

  // unified LDS: A hi/lo planes during K-loop; C staging after (F_GSTRIDE)
  __shared__ alignas(16) u16 AB[2 * 32 * 264];  // 33792 B
  u16* const Ah = AB;
  u16* const Al = AB + 32 * 264;

  const u16* Wsel = (chain == 0) ? W0 : (chain == 1 ? W1 : W2);
  if (F0 & F_BPERMAT) Wsel = W0 + (size_t)b * 65536;  // NG==1 only
  const u16* Whi = Wsel;
  const u16* Wlo = Whi + wLo;

  const int lane = tid & 63;
  const int w = tid >> 6;      // 8 waves, each owns 32 cols

  if constexpr (SF != 0u) {
    // ---- fused-agg staging: wave wv computes rows wv*4 .. wv*4+3,
    //      branchy interleaved exact gather across the 4 rows (R2) ----
    const float* __restrict__ gm = gsrc + (size_t)(chain * 8 + b) * GSTR + 256;
    const float* sb = (chain == 0) ? sb0 : (chain == 1 ? sb1 : sb2);
    const int c = lane * 4;
    float4 bb = *(const float4*)(sb + c);
    const int r0 = w * 4;
    int cnts[4];
    const int* ips[4];
    float4 av[4];
    int rowids[4];
#pragma unroll
    for (int i = 0; i < 4; i++) {
      rowids[i] = b * NN + bm + r0 + i;
      cnts[i] = ncnt[rowids[i]];
      ips[i] = nidx + (size_t)rowids[i] * CAP;
      av[i].x = av[i].y = av[i].z = av[i].w = 0.f;
    }
    int maxc = cnts[0];
    maxc = cnts[1] > maxc ? cnts[1] : maxc;
    maxc = cnts[2] > maxc ? cnts[2] : maxc;
    maxc = cnts[3] > maxc ? cnts[3] : maxc;
    for (int e = 0; e + 4 <= maxc; e += 4) {
#pragma unroll
      for (int i = 0; i < 4; i++) {
        if (e + 4 <= cnts[i]) {  // wave-uniform
          int4 i4 = *(const int4*)(ips[i] + e);
          float4 v0 = *(const float4*)(gm + ((size_t)i4.x << 8) + c);
          float4 v1 = *(const float4*)(gm + ((size_t)i4.y << 8) + c);
          float4 v2 = *(const float4*)(gm + ((size_t)i4.z << 8) + c);
          float4 v3 = *(const float4*)(gm + ((size_t)i4.w << 8) + c);
          av[i].x += v0.x + v1.x + v2.x + v3.x;
          av[i].y += v0.y + v1.y + v2.y + v3.y;
          av[i].z += v0.z + v1.z + v2.z + v3.z;
          av[i].w += v0.w + v1.w + v2.w + v3.w;
        }
      }
    }
#pragma unroll
    for (int i = 0; i < 4; i++) {
      for (int e = cnts[i] & ~3; e < cnts[i]; e++) {
        float4 v = *(const float4*)(gm + ((size_t)ips[i][e] << 8) + c);
        av[i].x += v.x; av[i].y += v.y; av[i].z += v.z; av[i].w += v.w;
      }
    }
#pragma unroll
    for (int i = 0; i < 4; i++) {
      float ov[4] = {av[i].x + bb.x, av[i].y + bb.y, av[i].z + bb.z, av[i].w + bb.w};
      float mv = (SF & F_MASKPOST) ? mask[rowids[i]] : 1.f;
      u16 hh[4], ll[4];
#pragma unroll
      for (int j = 0; j < 4; j++) {
        float t2 = ov[j];
        if (SF & F_SILU) t2 = t2 / (1.f + __expf(-t2));
        if (SF & F_MASKPOST) t2 *= mv;
        splitbf(t2, hh[j], ll[j]);
      }
      uint2 H; H.x = (u32)hh[0] | ((u32)hh[1] << 16); H.y = (u32)hh[2] | ((u32)hh[3] << 16);
      uint2 L; L.x = (u32)ll[0] | ((u32)ll[1] << 16); L.y = (u32)ll[2] | ((u32)ll[3] << 16);
      *(uint2*)&Ah[(r0 + i) * 264 + c] = H;
      *(uint2*)&Al[(r0 + i) * 264 + c] = L;
    }
  } else {
    // ---- copy staging from pre-split hi/lo planes (32 x 256) ----
    const u16* Abase = (chain == 0) ? A0 : (chain == 1 ? A1 : A2);
    const u16* Ahp = Abase + (size_t)b * MSZ;
    const u16* Alp = Ahp + aLo;
    {
      int s = tid;
      int r = s >> 4;
      int c = (s & 15) << 4;
      size_t ao = (size_t)(bm + r) * 256 + c;
      *(uint4*)&Ah[r * 264 + c] = *(const uint4*)(Ahp + ao);
      *(uint4*)&Ah[r * 264 + c + 8] = *(const uint4*)(Ahp + ao + 8);
      *(uint4*)&Al[r * 264 + c] = *(const uint4*)(Alp + ao);
      *(uint4*)&Al[r * 264 + c + 8] = *(const uint4*)(Alp + ao + 8);
    }
  }
  __syncthreads();

  const int m16 = lane & 15;
  const int q = lane >> 4;

  floatx4 acc[2][2];
#pragma unroll
  for (int i = 0; i < 2; i++)
#pragma unroll
    for (int j = 0; j < 2; j++) acc[i][j] = (floatx4){0.f, 0.f, 0.f, 0.f};

#pragma unroll
  for (int kk = 0; kk < 8; kk++) {
    short8 bh[2], bl2[2];
#pragma unroll
    for (int nt = 0; nt < 2; nt++) {
      int n = w * 32 + nt * 16 + m16;
      size_t off = (size_t)kk * 8192 + (size_t)n * 32 + (size_t)(((q + (n >> 1)) & 3) * 8);
      bh[nt] = *(const short8*)(Whi + off);
      bl2[nt] = *(const short8*)(Wlo + off);
    }
#pragma unroll
    for (int mt = 0; mt < 2; mt++) {
      int row = mt * 16 + m16;
      short8 ah = *(const short8*)&Ah[row * 264 + kk * 32 + q * 8];
      short8 al2 = *(const short8*)&Al[row * 264 + kk * 32 + q * 8];
#pragma unroll
      for (int nt = 0; nt < 2; nt++) {
        acc[mt][nt] = __builtin_amdgcn_mfma_f32_16x16x32_bf16(ah, bh[nt], acc[mt][nt], 0, 0, 0);
        acc[mt][nt] = __builtin_amdgcn_mfma_f32_16x16x32_bf16(al2, bh[nt], acc[mt][nt], 0, 0, 0);
        acc[mt][nt] = __builtin_amdgcn_mfma_f32_16x16x32_bf16(ah, bl2[nt], acc[mt][nt], 0, 0, 0);
      }
    }
  }

  if constexpr (DK) {
    // acc = silu(acc + b1[col]) in-registers, then second K-loop (A1 @ W1) on top
#pragma unroll
    for (int mt = 0; mt < 2; mt++)
#pragma unroll
      for (int nt = 0; nt < 2; nt++) {
        int col = w * 32 + nt * 16 + m16;
        float bp = b1[col];
#pragma unroll
        for (int r = 0; r < 4; r++) {
          float t2 = acc[mt][nt][r] + bp;
          acc[mt][nt][r] = t2 / (1.f + __expf(-t2));
        }
      }
    __syncthreads();  // all waves done reading Ah/Al from loop 1
    {
      const u16* Ahp = A1 + (size_t)b * MSZ;
      const u16* Alp = Ahp + aLo;
      int s = tid;
      int r = s >> 4;
      int c = (s & 15) << 4;
      size_t ao = (size_t)(bm + r) * 256 + c;
      *(uint4*)&Ah[r * 264 + c] = *(const uint4*)(Ahp + ao);
      *(uint4*)&Ah[r * 264 + c + 8] = *(const uint4*)(Ahp + ao + 8);
      *(uint4*)&Al[r * 264 + c] = *(const uint4*)(Alp + ao);
      *(uint4*)&Al[r * 264 + c + 8] = *(const uint4*)(Alp + ao + 8);
    }
    __syncthreads();
    const u16* W1h = W1;
    const u16* W1l = W1 + wLo;
#pragma unroll
    for (int kk = 0; kk < 8; kk++) {
      short8 bh[2], bl2[2];
#pragma unroll
      for (int nt = 0; nt < 2; nt++) {
        int n = w * 32 + nt * 16 + m16;
        size_t off = (size_t)kk * 8192 + (size_t)n * 32 + (size_t)(((q + (n >> 1)) & 3) * 8);
        bh[nt] = *(const short8*)(W1h + off);
        bl2[nt] = *(const short8*)(W1l + off);
      }
#pragma unroll
      for (int mt = 0; mt < 2; mt++) {
        int row = mt * 16 + m16;
        short8 ah = *(const short8*)&Ah[row * 264 + kk * 32 + q * 8];
        short8 al2 = *(const short8*)&Al[row * 264 + kk * 32 + q * 8];
#pragma unroll
        for (int nt = 0; nt < 2; nt++) {
          acc[mt][nt] = __builtin_amdgcn_mfma_f32_16x16x32_bf16(ah, bh[nt], acc[mt][nt], 0, 0, 0);
          acc[mt][nt] = __builtin_amdgcn_mfma_f32_16x16x32_bf16(al2, bh[nt], acc[mt][nt], 0, 0, 0);
          acc[mt][nt] = __builtin_amdgcn_mfma_f32_16x16x32_bf16(ah, bl2[nt], acc[mt][nt], 0, 0, 0);
        }
      }
    }
  }

  if constexpr ((F0 & F_GSTRIDE) != 0u) {
    // ---- G-output: LDS-staged full-line nontemporal write (L2 bypass) ----
    void* op = (NG == 1 || chain == 0) ? o0 : (chain == 1 ? o1 : o2);
    __syncthreads();                  // A reads complete; AB is dead
    float* Cf = (float*)AB;           // 32 x 256 f32 = 32 KB (fits 33.8 KB)
#pragma unroll
    for (int mt = 0; mt < 2; mt++)
#pragma unroll
      for (int nt = 0; nt < 2; nt++) {
        int col = w * 32 + nt * 16 + m16;
#pragma unroll
        for (int r = 0; r < 4; r++)
          Cf[(mt * 16 + q * 4 + r) * 256 + col] = acc[mt][nt][r];
      }
    __syncthreads();
    int r2 = tid >> 4;                // 32 rows, 16 threads/row
    int cs = (tid & 15) * 16;         // 16 floats = 64 B per thread
    float* dst = (float*)op + (size_t)b * GSTR + (size_t)(bm + r2) * 256 + cs;
    const float* srcp = Cf + r2 * 256 + cs;
#pragma unroll
    for (int j = 0; j < 4; j++) {
      floatx4 v4 = *(const floatx4*)(srcp + j * 4);
      __builtin_nontemporal_store(v4, (floatx4*)(dst + j * 4));
    }
  } else if (NG == 1 || chain == 0) {
    gemm_epi<F0>(acc, b, bm, w, m16, q, b0, mask, xf32, gma, bta, bmu, bvr, addt, o0, oLo);
  } else if (chain == 1) {
    gemm_epi<F1>(acc, b, bm, w, m16, q, b1, mask, xf32, gma, bta, bmu, bvr, addt, o1, oLo);
  } else {
    gemm_epi<F2>(acc, b, bm, w, m16, q, b2, mask, xf32, gma, bta, bmu, bvr, addt, o2, oLo);
  }
}

// ---------------------------------------------------------------------------
// kv[d][e] = sum_n pk[n][d] * pv[n][e], from transposed bf16 hi/lo planes.
// LDS-free, 3-term. Split-K=8: part[z = p*8+b][d][e], grid (2,2,64).
// ---------------------------------------------------------------------------
__global__ __launch_bounds__(256, 2) void kv_k(
    const u16* __restrict__ pkT, const u16* __restrict__ pvT, float* __restrict__ part)
{
  int et = blockIdx.x * 128;
  int dt = blockIdx.y * 128;
  int z = blockIdx.z;
  int b = z & 7;
  int p = z >> 3;
  int tid = threadIdx.x;
  int lane = tid & 63, w = tid >> 6;
  int m16 = lane & 15, q = lane >> 4;

  const u16* pkh = pkT + (size_t)b * TP_MAT;
  const u16* pkl = pkh + TP_LO;
  const u16* pvh = pvT + (size_t)b * TP_MAT;
  const u16* pvl = pvh + TP_LO;

  int d_base = dt + (w >> 1) * 64 + m16;
  int e_base = et + (w & 1) * 64 + m16;

  floatx4 acc[4][4];
#pragma unroll
  for (int i = 0; i < 4; i++)
#pragma unroll
    for (int j = 0; j < 4; j++) acc[i][j] = (floatx4){0.f, 0.f, 0.f, 0.f};

#pragma unroll
  for (int kt = 0; kt < 8; kt++) {
    int kc = p * 256 + kt * 32 + q * 8;
    short8 ah[4], al[4], bh[4], bl[4];
#pragma unroll
    for (int mt = 0; mt < 4; mt++) {
      size_t o = (size_t)(d_base + mt * 16) * 2048 + kc;
      ah[mt] = *(const short8*)(pkh + o);
      al[mt] = *(const short8*)(pkl + o);
    }
#pragma unroll
    for (int nt = 0; nt < 4; nt++) {
      size_t o = (size_t)(e_base + nt * 16) * 2048 + kc;
      bh[nt] = *(const short8*)(pvh + o);
      bl[nt] = *(const short8*)(pvl + o);
    }
#pragma unroll
    for (int mt = 0; mt < 4; mt++)
#pragma unroll
      for (int nt = 0; nt < 4; nt++) {
        acc[mt][nt] = __builtin_amdgcn_mfma_f32_16x16x32_bf16(ah[mt], bh[nt], acc[mt][nt], 0, 0, 0);
        acc[mt][nt] = __builtin_amdgcn_mfma_f32_16x16x32_bf16(al[mt], bh[nt], acc[mt][nt], 0, 0, 0);
        acc[mt][nt] = __builtin_amdgcn_mfma_f32_16x16x32_bf16(ah[mt], bl[nt], acc[mt][nt], 0, 0, 0);
      }
  }

#pragma unroll
  for (int mt = 0; mt < 4; mt++)
#pragma unroll
    for (int r = 0; r < 4; r++) {
      int d = dt + (w >> 1) * 64 + mt * 16 + q * 4 + r;
#pragma unroll
      for (int nt = 0; nt < 4; nt++) {
        int e = et + (w & 1) * 64 + nt * 16 + m16;
        part[(size_t)z * 65536 + (size_t)d * 256 + e] = acc[mt][nt][r];
      }
    }
}

// Reduce split-K partials (8 p-planes) and emit kv bf16 hi/lo swizzled planes.
__global__ __launch_bounds__(256) void kv_conv_k(const float* __restrict__ part, u16* __restrict__ dst)
{
  int gid = blockIdx.x * 256 + threadIdx.x;  // 8 * 8192 = 65536
  int b = gid >> 13;
  int rem = gid & 8191;
  int kb = rem >> 10;
  int e = (rem >> 2) & 255;
  int slot = rem & 3;
  int qv = (slot - (e >> 1)) & 3;
  int d0 = kb * 32 + qv * 8;
  const float* src = part + (size_t)b * 65536 + (size_t)d0 * 256 + e;
  u32 oh[4], ol[4];
#pragma unroll
  for (int t2 = 0; t2 < 4; t2++) {
    float s0 = 0.f, s1 = 0.f;
#pragma unroll
    for (int pp = 0; pp < 8; pp++) {
      const float* sp = src + (size_t)pp * 524288 + t2 * 512;
      s0 += sp[0];
      s1 += sp[256];
    }
    u16 h0, l0, h1, l1;
    splitbf(s0, h0, l0);
    splitbf(s1, h1, l1);
    oh[t2] = (u32)h0 | ((u32)h1 << 16);
    ol[t2] = (u32)l0 | ((u32)l1 << 16);
  }
  uint4 qh; qh.x = oh[0]; qh.y = oh[1]; qh.z = oh[2]; qh.w = oh[3];
  uint4 ql; ql.x = ol[0]; ql.y = ol[1]; ql.z = ol[2]; ql.w = ol[3];
  *(uint4*)(dst + (size_t)gid * 8) = qh;
  *(uint4*)(dst + 524288 + (size_t)gid * 8) = ql;
}

// ---------------------------------------------------------------------------
extern "C" void kernel_launch(void* const* d_in, const int* in_sizes, int n_in,
                              void* d_out, int out_size, void* d_ws, size_t ws_size,
                              hipStream_t stream)
{
  const float* x = (const float*)d_in[0];
  const float* adj = (const float*)d_in[1];
  const float* mask = (const float*)d_in[2];
  const float* W_lin = (const float*)d_in[3];
  const float* b_lin = (const float*)d_in[4];
  const float* Wq_mp = (const float*)d_in[5];
  const float* bq_mp = (const float*)d_in[6];
  const float* Wk_mp = (const float*)d_in[7];
  const float* bk_mp = (const float*)d_in[8];
  const float* Wv_mp = (const float*)d_in[9];
  const float* bv_mp = (const float*)d_in[10];
  const float* Wk_att = (const float*)d_in[11];
  const float* Wv_att = (const float*)d_in[12];
  const float* Wq_att = (const float*)d_in[13];
  const float* Wo_att = (const float*)d_in[14];
  const float* bn_gamma = (const float*)d_in[15];
  const float* bn_beta = (const float*)d_in[16];
  const float* bn_mean = (const float*)d_in[17];
  const float* bn_var = (const float*)d_in[18];
  const float* W_proj = (const float*)d_in[19];
  const float* b_proj = (const float*)d_in[20];
  const float* W_res = (const float*)d_in[21];
  const float* b_res = (const float*)d_in[22];

  char* ws = (char*)d_ws;
  int* CNT    = (int*)(ws + 0);                 // 64 KB
  int* IDX    = (int*)(ws + (1ull << 20));      // 4 MB
  u16* WSZ    = (u16*)(ws + (5ull << 20));      // 4 MB (bf16 hi 2MB + lo 2MB)
  u16* KVS    = (u16*)(ws + (9ull << 20));      // 2 MB
  float* KVP  = (float*)(ws + (11ull << 20));   // 16 MB
  u16* XHL    = (u16*)(ws + (27ull << 20));     // 16 MB (8 hi + 8 lo)
  u16* HHL    = (u16*)(ws + (43ull << 20));     // 16 MB (8 hi + 8 lo)
  float* GA   = (float*)(ws + (59ull << 20));   // 50.4 MB fp32 (24 gapped mats)
  float* GB   = (float*)(ws + (110ull << 20));  // 50.4 MB fp32 (ping-pong)
  u16* PKT    = (u16*)(ws + (161ull << 20));    // 16 MB
  u16* PVT    = (u16*)(ws + (177ull << 20));    // 16 MB
  u16* ATT    = (u16*)(ws + (193ull << 20));    // 16 MB
  u16* YHL    = (u16*)(ws + (209ull << 20));    // 16 MB
  u16* PQHL   = (u16*)(ws + (225ull << 20));    // 16 MB -> total 241 MB

  const size_t WLO = 1048576;   // weight lo-plane offset (u16 elems)
  const size_t KLO = 524288;    // kv lo-plane offset
  const size_t A8  = 8 * MSZ;   // lo offset for 8-mat hi/lo buffers
  const unsigned FG = F_GSTRIDE;  // G-output epi flags (LDS-staged NT writes)

  // --- prologue: weight conv + x conv + neighbor lists + G gap zero ---
  WPtrs wp;
  wp.p[0] = W_lin;
  wp.p[1] = Wq_mp; wp.p[2] = Wq_mp + 65536; wp.p[3] = Wq_mp + 131072;
  wp.p[4] = Wk_mp; wp.p[5] = Wk_mp + 65536; wp.p[6] = Wk_mp + 131072;
  wp.p[7] = Wv_mp; wp.p[8] = Wv_mp + 65536; wp.p[9] = Wv_mp + 131072;
  wp.p[10] = Wk_att; wp.p[11] = Wv_att; wp.p[12] = Wq_att; wp.p[13] = Wo_att;
  wp.p[14] = W_proj; wp.p[15] = W_res;
  prologue_k<<<21040, 256, 0, stream>>>(wp, WSZ, x, XHL, A8, adj, CNT, IDX, GA, GB);

  // --- h = x @ W_lin + b_lin -> hi/lo planes ---
  gemm_k<1, 0u, F_BIAS | F_OUTHL, 0u, 0u><<<512, 512, 0, stream>>>(
      XHL, XHL, XHL, A8, WSZ, WSZ, WSZ, WLO,
      b_lin, nullptr, nullptr, mask, nullptr,
      bn_gamma, bn_beta, bn_mean, bn_var, nullptr,
      HHL, nullptr, nullptr, A8,
      nullptr, nullptr, nullptr, nullptr, CNT, IDX);

  // --- mp step 0: G0 = h @ W[0] (dense copy staging, gapped NT out) ---
  gemm_k<3, 0u, FG, FG, FG><<<1536, 512, 0, stream>>>(
      HHL, HHL, HHL, A8,
      WSZ + (size_t)1 * 65536, WSZ + (size_t)4 * 65536, WSZ + (size_t)7 * 65536, WLO,
      nullptr, nullptr, nullptr, mask, nullptr,
      bn_gamma, bn_beta, bn_mean, bn_var, nullptr,
      GA + 256, GA + 8 * GSTR + 256, GA + 16 * GSTR + 256, 0,
      nullptr, nullptr, nullptr, nullptr, CNT, IDX);

  // --- mp steps 1..5: fused-agg staging (A = silu(agg(G_prev)+b)), G ping-pong
  for (int s = 1; s < 6; s++) {
    int iw = s >> 1;            // weight index for this step
    int ib = (s - 1) >> 1;      // bias index of the fused agg (prev step)
    float* Gin = (s & 1) ? GA : GB;
    float* Gout = (s & 1) ? GB : GA;
    gemm_k<3, F_BIAS | F_SILU, FG, FG, FG><<<1536, 512, 0, stream>>>(
        nullptr, nullptr, nullptr, 0,
        WSZ + (size_t)(1 + iw) * 65536, WSZ + (size_t)(4 + iw) * 65536,
        WSZ + (size_t)(7 + iw) * 65536, WLO,
        nullptr, nullptr, nullptr, mask, nullptr,
        bn_gamma, bn_beta, bn_mean, bn_var, nullptr,
        Gout + 256, Gout + 8 * GSTR + 256, Gout + 16 * GSTR + 256, 0,
        Gin, bq_mp + ib * 256, bk_mp + ib * 256, bv_mp + ib * 256, CNT, IDX);
  }
  // G_5 lives in GB (s=5 wrote GB)

  // --- attention projections, fused final-agg staging + (pq | pk | pv) epis ---
  gemm_k<3, F_BIAS | F_SILU | F_MASKPOST,
         F_OUTHL, F_SILU | F_MASKPRE | F_TPLANES, F_MASKPOST | F_TPLANES>
      <<<1536, 512, 0, stream>>>(
      nullptr, nullptr, nullptr, 0,
      WSZ + (size_t)12 * 65536, WSZ + (size_t)10 * 65536, WSZ + (size_t)11 * 65536, WLO,
      nullptr, nullptr, nullptr, mask, nullptr,
      bn_gamma, bn_beta, bn_mean, bn_var, nullptr,
      PQHL, PKT, PVT, A8,
      GB, bq_mp + 512, bk_mp + 512, bv_mp + 512, CNT, IDX);

  // --- kv = pk^T pv ---
  kv_k<<<dim3(2, 2, 64), 256, 0, stream>>>(PKT, PVT, KVP);
  kv_conv_k<<<256, 256, 0, stream>>>(KVP, KVS);

  // --- attn = pq @ kv -> hi/lo ---
  gemm_k<1, 0u, F_BPERMAT | F_OUTHL, 0u, 0u><<<512, 512, 0, stream>>>(
      PQHL, PQHL, PQHL, A8, KVS, KVS, KVS, KLO,
      nullptr, nullptr, nullptr, mask, nullptr,
      bn_gamma, bn_beta, bn_mean, bn_var, nullptr,
      ATT, nullptr, nullptr, A8,
      nullptr, nullptr, nullptr, nullptr, CNT, IDX);

  // --- y = BN(attn @ Wo + x) -> hi/lo ---
  gemm_k<1, 0u, F_ADDX | F_BN | F_OUTHL, 0u, 0u><<<512, 512, 0, stream>>>(
      ATT, ATT, ATT, A8,
      WSZ + (size_t)13 * 65536, nullptr, nullptr, WLO,
      nullptr, nullptr, nullptr, mask, x,
      bn_gamma, bn_beta, bn_mean, bn_var, nullptr,
      YHL, nullptr, nullptr, A8,
      nullptr, nullptr, nullptr, nullptr, CNT, IDX);

  // --- out = (silu(y @ W_proj + b_proj) + x @ W_res + b_res) * mask, dual-K ---
  gemm_k<1, 0u, F_BIAS | F_MASKPOST, 0u, 0u, true><<<512, 512, 0, stream>>>(
      YHL, XHL, YHL, A8,
      WSZ + (size_t)14 * 65536, WSZ + (size_t)15 * 65536, nullptr, WLO,
      b_res, b_proj, nullptr, mask, nullptr,
      bn_gamma, bn_beta, bn_mean, bn_var, nullptr,
      d_out, nullptr, nullptr, 0,
      nullptr, nullptr, nullptr, nullptr, CNT, IDX);

  (void)in_sizes; (void)n_in; (void)out_size; (void)ws_size;
}

// Round 11
// 839.537 us; speedup vs baseline: 1.1808x; 1.1808x over previous
//
#include <hip/hip_runtime.h>
#include <stdint.h>

#define NB 8
#define NN 2048
#define NU 256
#define CAP 64
#define BNEPS 0.001f
#define GSTR ((size_t)(NN * NU + 256))   // G mat stride in floats (256-float zero gap BEFORE each mat)

// Per-wave LDS region (u16 units / bytes): 2256 u16 = 4512 B.
//  gather phase: ring 4 x 1024B at [0,4096), idx 256B at [4096,4352)
//  MFMA phase:   Ah rows (4 x 264 u16) at [0,1056), Al at [1056,2112)
// Region stride 4512B = 1128 dwords, 1128%32=8 -> A-row starting banks spread
// 2-way across a 16-lane MFMA fragment read (free per LDS bank rules).
#define REG16 2256
#define REGB  4512

typedef __attribute__((ext_vector_type(8))) short short8;
typedef __attribute__((ext_vector_type(4))) float floatx4;
typedef unsigned short u16;
typedef unsigned int u32;

__device__ __forceinline__ float bf2f(u16 u) {
  union { u32 i; float f; } c; c.i = ((u32)u) << 16; return c.f;
}
__device__ __forceinline__ u16 f2bf(float f) {
  union { float f; u32 i; } c; c.f = f;
  return (u16)((c.i + 0x7fffu + ((c.i >> 16) & 1u)) >> 16);
}
// bf16 hi/lo split: a = bf2f(h) + bf2f(l) + O(2^-18 |a|)
__device__ __forceinline__ void splitbf(float a, u16& h, u16& l) {
  h = f2bf(a);
  l = f2bf(a - bf2f(h));
}

// Async global->LDS DMA: per-lane global address, wave-uniform LDS base
// (HW adds lane*size to the LDS destination). Counted by vmcnt.
__device__ __forceinline__ void gld_lds16(const float* g, void* l) {
  __builtin_amdgcn_global_load_lds(
      (const __attribute__((address_space(1))) u32*)g,
      (__attribute__((address_space(3))) u32*)l, 16, 0, 0);
}
__device__ __forceinline__ void gld_lds4(const int* g, void* l) {
  __builtin_amdgcn_global_load_lds(
      (const __attribute__((address_space(1))) u32*)g,
      (__attribute__((address_space(3))) u32*)l, 4, 0, 0);
}

#define WAITV0 { asm volatile("s_waitcnt vmcnt(0)" ::: "memory"); __builtin_amdgcn_sched_barrier(0); }
#define WAITV2 { asm volatile("s_waitcnt vmcnt(2)" ::: "memory"); __builtin_amdgcn_sched_barrier(0); }

enum : unsigned {
  F_BIAS = 2u, F_SILU = 4u, F_MASKPRE = 8u, F_MASKPOST = 16u,
  F_ADDX = 32u, F_BN = 64u, F_ADDT = 128u, F_BPERMAT = 512u,
  F_TPLANES = 1024u, F_OUTHL = 2048u, F_GSTRIDE = 8192u
};

#define TP_MAT 524288   // per-batch transposed plane: 256 cols x 2048 rows (u16)
#define TP_LO  4194304  // transposed lo plane offset (u16 elems)
#define MSZ ((size_t)NN * NU)

struct WPtrs { const float* p[16]; };

// ---------------------------------------------------------------------------
// Merged prologue: [0,512) weight conv, [512,4608) x conv, [4608,20992) nbr
// (pads idx rows to CAP with -1), [20992,21040) zero the G mat gaps.
// ---------------------------------------------------------------------------
__global__ __launch_bounds__(256) void prologue_k(
    WPtrs wp, u16* __restrict__ wdst,
    const float* __restrict__ x, u16* __restrict__ xdst, size_t xLo,
    const float* __restrict__ adj, int* __restrict__ cnt, int* __restrict__ idx,
    float* __restrict__ ga, float* __restrict__ gb)
{
  int bid = blockIdx.x;
  int tid = threadIdx.x;
  __shared__ int c0;
  if (bid < 512) {
    // weight conversion: f32 [K=256][N=256] -> TWO bf16 swizzled-B^T planes
    int gid = bid * 256 + tid;  // 16 mats * 8192 chunks
    int mat = gid >> 13;
    int rem = gid & 8191;
    int kb = rem >> 10;
    int n = (rem >> 2) & 255;
    int slot = rem & 3;
    int qv = (slot - (n >> 1)) & 3;
    int k0 = kb * 32 + qv * 8;
    const float* W = wp.p[mat];
    u32 oh[4], ol[4];
#pragma unroll
    for (int t2 = 0; t2 < 4; t2++) {
      float f0 = W[(size_t)(k0 + 2 * t2) * 256 + n];
      float f1 = W[(size_t)(k0 + 2 * t2 + 1) * 256 + n];
      u16 h0, l0, h1, l1;
      splitbf(f0, h0, l0);
      splitbf(f1, h1, l1);
      oh[t2] = (u32)h0 | ((u32)h1 << 16);
      ol[t2] = (u32)l0 | ((u32)l1 << 16);
    }
    uint4 qh; qh.x = oh[0]; qh.y = oh[1]; qh.z = oh[2]; qh.w = oh[3];
    uint4 ql; ql.x = ol[0]; ql.y = ol[1]; ql.z = ol[2]; ql.w = ol[3];
    *(uint4*)(wdst + (size_t)gid * 8) = qh;
    *(uint4*)(wdst + 1048576 + (size_t)gid * 8) = ql;
  } else if (bid < 4608) {
    // x conversion: fp32 -> row-major hi/lo bf16 planes
    size_t i = ((size_t)(bid - 512) * 256 + tid) * 4;
    float4 v = *(const float4*)(x + i);
    u16 h0, l0, h1, l1, h2, l2, h3, l3;
    splitbf(v.x, h0, l0); splitbf(v.y, h1, l1);
    splitbf(v.z, h2, l2); splitbf(v.w, h3, l3);
    uint2 H; H.x = (u32)h0 | ((u32)h1 << 16); H.y = (u32)h2 | ((u32)h3 << 16);
    uint2 L; L.x = (u32)l0 | ((u32)l1 << 16); L.y = (u32)l2 | ((u32)l3 << 16);
    *(uint2*)(xdst + i) = H;
    *(uint2*)(xdst + xLo + i) = L;
  } else if (bid < 20992) {
    // neighbor-list build: one block per (b,m) row of adj; values exactly 0/1
    int row = bid - 4608;
    const float* base = adj + (size_t)row * NN;
    if (tid == 0) c0 = 0;
    __syncthreads();
#pragma unroll
    for (int j = 0; j < 8; j++) {
      int n = j * 256 + tid;  // coalesced
      if (base[n] != 0.f) {
        int p = atomicAdd(&c0, 1);
        if (p < CAP) idx[(size_t)row * CAP + p] = n;
      }
    }
    __syncthreads();
    int cc = (c0 < CAP ? c0 : CAP);
    // pad to CAP with sentinel -1 (points at the zero gap before each G mat)
    for (int p = cc + tid; p < CAP; p += 256) idx[(size_t)row * CAP + p] = -1;
    if (tid == 0) cnt[row] = cc;
  } else {
    // zero the 256-float gap before each of the 24 mats in GA and GB
    int g = bid - 20992;           // 0..47
    float* base = (g < 24 ? ga : gb) + (size_t)(g % 24) * GSTR;
    base[tid] = 0.f;
  }
}

// ---------------------------------------------------------------------------
// Per-chain epilogue (compile-time flags). Wave layout: 32 rows x 32 cols
// (mt=2 row tiles, nt=2 col tiles), wave w owns cols [w*32, w*32+32).
// F_GSTRIDE: fp32 out with per-b stride GSTR (gapped G layout). Plain stores
// everywhere (NT stores amplify writes ~2-3x on gfx950 — R3/R10 lesson).
// ---------------------------------------------------------------------------
template <unsigned F>
__device__ __forceinline__ void gemm_epi(
    floatx4 (&acc)[2][2], int b, int bm, int w, int m16, int q,
    const float* __restrict__ bias, const float* __restrict__ mask,
    const float* __restrict__ xf32,
    const float* __restrict__ gma, const float* __restrict__ bta,
    const float* __restrict__ bmu, const float* __restrict__ bvr,
    const float* __restrict__ addt, void* __restrict__ outp, size_t oLo)
{
#pragma unroll
  for (int mt = 0; mt < 2; mt++) {
    if (F & F_TPLANES) {
      u16* oh = (u16*)outp + (size_t)b * TP_MAT;
      u16* ol = oh + TP_LO;
      int gr0 = bm + mt * 16 + q * 4;
#pragma unroll
      for (int nt = 0; nt < 2; nt++) {
        int col = w * 32 + nt * 16 + m16;
        u16 hh[4], ll[4];
#pragma unroll
        for (int r = 0; r < 4; r++) {
          float t2 = acc[mt][nt][r];
          float mv = mask[b * NN + gr0 + r];
          if (F & F_MASKPRE) t2 *= mv;
          if (F & F_SILU) t2 = t2 / (1.f + __expf(-t2));
          if (F & F_MASKPOST) t2 *= mv;
          splitbf(t2, hh[r], ll[r]);
        }
        uint2 H2, L2v;
        H2.x = (u32)hh[0] | ((u32)hh[1] << 16);
        H2.y = (u32)hh[2] | ((u32)hh[3] << 16);
        L2v.x = (u32)ll[0] | ((u32)ll[1] << 16);
        L2v.y = (u32)ll[2] | ((u32)ll[3] << 16);
        *(uint2*)(oh + (size_t)col * 2048 + gr0) = H2;
        *(uint2*)(ol + (size_t)col * 2048 + gr0) = L2v;
      }
    } else {
#pragma unroll
      for (int r = 0; r < 4; r++) {
        int gr = bm + mt * 16 + q * 4 + r;
        float mval = 1.f;
        if (F & (F_MASKPRE | F_MASKPOST)) mval = mask[b * NN + gr];
#pragma unroll
        for (int nt = 0; nt < 2; nt++) {
          int col = w * 32 + nt * 16 + m16;
          float t2 = acc[mt][nt][r];
          if (F & F_BIAS) t2 += bias[col];
          if (F & F_MASKPRE) t2 *= mval;
          if (F & F_SILU) t2 = t2 / (1.f + __expf(-t2));
          if (F & F_ADDX) t2 += xf32[((size_t)b * NN + gr) * NU + col];
          if (F & F_BN) t2 = gma[col] * (t2 - bmu[col]) * rsqrtf(bvr[col] + BNEPS) + bta[col];
          if (F & F_ADDT) t2 += addt[((size_t)b * NN + gr) * NU + col];
          if (F & F_MASKPOST) t2 *= mval;
          size_t o;
          if (F & F_GSTRIDE) o = (size_t)b * GSTR + (size_t)gr * NU + col;
          else o = ((size_t)b * NN + gr) * NU + col;
          if (F & F_OUTHL) {
            u16 h0, l0;
            splitbf(t2, h0, l0);
            ((u16*)outp)[o] = h0;
            ((u16*)outp)[o + oLo] = l0;
          } else {
            ((float*)outp)[o] = t2;
          }
        }
      }
    }
  }
}

// ---------------------------------------------------------------------------
// Dense GEMM, fp32-emulated via bf16 hi/lo 3-term MFMA. Up to 3 fused chains.
// Tile 32 rows x 256 cols, 512 thr = 8 waves, each 32x32 (B unique per wave).
// LDS: 8 per-wave regions of 4512B = 36096B -> 4 blocks/CU (lb 512,8).
// A-staging modes (compile-time SF):
//   SF == 0 : A pre-split hi/lo planes, pure-copy staged to LDS.
//   SF != 0 : FUSED AGGREGATION via LDS-RING DMA (theory-B test): each wave
//             owns 4 rows; per row, the idx list is DMA'd to LDS, then G rows
//             are DMA'd 1KB-at-a-time into a 4-slot ring with counted
//             vmcnt(2) waits (never draining in steady state) — zero result
//             VGPRs, so ~50-100KB of gather data in flight per CU (vs ~2KB
//             for VGPR loads in R2/R7/R8). Accumulation order bit-identical:
//             ((v0+v1)+v2)+v3 per 4-group, sequential tail.
// DK : dual-K mode (NG==1): after chain-0 K-loop, acc = silu(acc + b1[col]),
//      restage A from A1, second K-loop with W1 accumulating.
// B: per-lane fragments straight from swizzled global planes (L2-hot).
// Grid 1-D, xcd = id&7. NG==3 grid 1536, chain-major (t>>6), 64 tiles/chain.
// NOTE: cross-dispatch L2 reuse impossible (dispatch-boundary release/acquire,
// non-coherent per-XCD L2s) — R5/R6 lesson. NT stores banned — R3/R10 lesson.
// ---------------------------------------------------------------------------
template <int NG, unsigned SF, unsigned F0, unsigned F1, unsigned F2, bool DK = false>
__global__ __launch_bounds__(512, 8) void gemm_k(
    const u16* __restrict__ A0, const u16* __restrict__ A1, const u16* __restrict__ A2,
    size_t aLo,
    const u16* __restrict__ W0, const u16* __restrict__ W1, const u16* __restrict__ W2,
    size_t wLo,
    const float* __restrict__ b0, const float* __restrict__ b1, const float* __restrict__ b2,
    const float* __restrict__ mask,
    const float* __restrict__ xf32,
    const float* __restrict__ gma, const float* __restrict__ bta,
    const float* __restrict__ bmu, const float* __restrict__ bvr,
    const float* __restrict__ addt,
    void* __restrict__ o0, void* __restrict__ o1, void* __restrict__ o2,
    size_t oLo,
    const float* __restrict__ gsrc,
    const float* __restrict__ sb0, const float* __restrict__ sb1, const float* __restrict__ sb2,
    const int* __restrict__ ncnt, const int* __restrict__ nidx)
{
  const int tid = threadIdx.x;
  const int id = blockIdx.x;
  const int xcd = id & 7;
  const int t = id >> 3;
  const int chain = (NG == 1) ? 0 : (t >> 6);   // chain-major: 64 tiles/chain
  const int xt = (NG == 1) ? t : (t & 63);
  const int b = xcd;
  const int bm = xt * 32;

  __shared__ alignas(16) u16 AB[8 * REG16];   // 36096 B

  const u16* Wsel = (chain == 0) ? W0 : (chain == 1 ? W1 : W2);
  if (F0 & F_BPERMAT) Wsel = W0 + (size_t)b * 65536;  // NG==1 only
  const u16* Whi = Wsel;
  const u16* Wlo = Whi + wLo;

  const int lane = tid & 63;
  const int w = tid >> 6;      // 8 waves, each owns 32 cols

  if constexpr (SF != 0u) {
    // ---- fused-agg staging via LDS-ring DMA: wave w computes rows w*4..+3 --
    const float* __restrict__ gm = gsrc + (size_t)(chain * 8 + b) * GSTR + 256;
    const float* sb = (chain == 0) ? sb0 : (chain == 1 ? sb1 : sb2);
    const int c4 = lane * 4;
    float4 bb = *(const float4*)(sb + c4);
    char* const wreg = (char*)AB + w * REGB;  // this wave's region
    char* const ring = wreg;                  // 4 x 1024B slots
    int* const idxl = (int*)(wreg + 4096);    // 64 ints

    float4 av4[4];
    int cnts[4], rowids[4];
    const int* ips[4];
#pragma unroll
    for (int i = 0; i < 4; i++) {
      rowids[i] = b * NN + bm + w * 4 + i;
      cnts[i] = ncnt[rowids[i]];
      ips[i] = nidx + (size_t)rowids[i] * CAP;
    }

#pragma unroll 1
    for (int i = 0; i < 4; i++) {
      const int cnt = cnts[i];
      float4 a; a.x = a.y = a.z = a.w = 0.f;
      // DMA this row's idx list into LDS (lane l loads idx[l]); drain.
      gld_lds4(ips[i] + lane, idxl);
      WAITV0;
      const int cnt4 = cnt & ~3;
      if (cnt4 > 0) {
        int4 i0 = *(const int4*)idxl;
        gld_lds16(gm + ((size_t)i0.x << 8) + c4, ring);
        gld_lds16(gm + ((size_t)i0.y << 8) + c4, ring + 1024);
        gld_lds16(gm + ((size_t)i0.z << 8) + c4, ring + 2048);
        gld_lds16(gm + ((size_t)i0.w << 8) + c4, ring + 3072);
#pragma unroll 1
        for (int e = 4; e < cnt4; e += 4) {
          int4 nx = *(const int4*)(idxl + e);
          WAITV2;  // oldest 2 (slots 0,1) done
          float4 v0 = *(const float4*)(ring + lane * 16);
          float4 v1 = *(const float4*)(ring + 1024 + lane * 16);
          float4 tt;
          tt.x = v0.x + v1.x; tt.y = v0.y + v1.y;
          tt.z = v0.z + v1.z; tt.w = v0.w + v1.w;
          gld_lds16(gm + ((size_t)nx.x << 8) + c4, ring);
          gld_lds16(gm + ((size_t)nx.y << 8) + c4, ring + 1024);
          WAITV2;  // slots 2,3 done (next group's 0,1 still in flight)
          float4 v2 = *(const float4*)(ring + 2048 + lane * 16);
          float4 v3 = *(const float4*)(ring + 3072 + lane * 16);
          tt.x = (tt.x + v2.x) + v3.x; tt.y = (tt.y + v2.y) + v3.y;
          tt.z = (tt.z + v2.z) + v3.z; tt.w = (tt.w + v2.w) + v3.w;
          a.x += tt.x; a.y += tt.y; a.z += tt.z; a.w += tt.w;
          gld_lds16(gm + ((size_t)nx.z << 8) + c4, ring + 2048);
          gld_lds16(gm + ((size_t)nx.w << 8) + c4, ring + 3072);
        }
        // drain last group
        WAITV2;
        float4 v0 = *(const float4*)(ring + lane * 16);
        float4 v1 = *(const float4*)(ring + 1024 + lane * 16);
        float4 tt;
        tt.x = v0.x + v1.x; tt.y = v0.y + v1.y;
        tt.z = v0.z + v1.z; tt.w = v0.w + v1.w;
        WAITV0;
        float4 v2 = *(const float4*)(ring + 2048 + lane * 16);
        float4 v3 = *(const float4*)(ring + 3072 + lane * 16);
        tt.x = (tt.x + v2.x) + v3.x; tt.y = (tt.y + v2.y) + v3.y;
        tt.z = (tt.z + v2.z) + v3.z; tt.w = (tt.w + v2.w) + v3.w;
        a.x += tt.x; a.y += tt.y; a.z += tt.z; a.w += tt.w;
      }
      // tail singles, exact sequential order
#pragma unroll 1
      for (int e = cnt4; e < cnt; e++) {
        int n = idxl[e];
        gld_lds16(gm + ((size_t)n << 8) + c4, ring);
        WAITV0;
        float4 v = *(const float4*)(ring + lane * 16);
        a.x += v.x; a.y += v.y; a.z += v.z; a.w += v.w;
      }
      av4[i] = a;
    }

    // ring dead; write this wave's A rows (hi/lo) into its region
#pragma unroll
    for (int i = 0; i < 4; i++) {
      float ov[4] = {av4[i].x + bb.x, av4[i].y + bb.y, av4[i].z + bb.z, av4[i].w + bb.w};
      float mv = (SF & F_MASKPOST) ? mask[rowids[i]] : 1.f;
      u16 hh[4], ll[4];
#pragma unroll
      for (int j = 0; j < 4; j++) {
        float t2 = ov[j];
        if (SF & F_SILU) t2 = t2 / (1.f + __expf(-t2));
        if (SF & F_MASKPOST) t2 *= mv;
        splitbf(t2, hh[j], ll[j]);
      }
      uint2 H; H.x = (u32)hh[0] | ((u32)hh[1] << 16); H.y = (u32)hh[2] | ((u32)hh[3] << 16);
      uint2 L; L.x = (u32)ll[0] | ((u32)ll[1] << 16); L.y = (u32)ll[2] | ((u32)ll[3] << 16);
      *(uint2*)&AB[w * REG16 + i * 264 + c4] = H;
      *(uint2*)&AB[w * REG16 + 1056 + i * 264 + c4] = L;
    }
  } else {
    // ---- copy staging from pre-split hi/lo planes (32 x 256) ----
    const u16* Abase = (chain == 0) ? A0 : (chain == 1 ? A1 : A2);
    const u16* Ahp = Abase + (size_t)b * MSZ;
    const u16* Alp = Ahp + aLo;
    {
      int s = tid;
      int r = s >> 4;
      int c = (s & 15) << 4;
      size_t ao = (size_t)(bm + r) * 256 + c;
      int base = (r >> 2) * REG16 + (r & 3) * 264 + c;
      *(uint4*)&AB[base] = *(const uint4*)(Ahp + ao);
      *(uint4*)&AB[base + 8] = *(const uint4*)(Ahp + ao + 8);
      *(uint4*)&AB[base + 1056] = *(const uint4*)(Alp + ao);
      *(uint4*)&AB[base + 1056 + 8] = *(const uint4*)(Alp + ao + 8);
    }
  }
  __syncthreads();

  const int m16 = lane & 15;
  const int q = lane >> 4;

  floatx4 acc[2][2];
#pragma unroll
  for (int i = 0; i < 2; i++)
#pragma unroll
    for (int j = 0; j < 2; j++) acc[i][j] = (floatx4){0.f, 0.f, 0.f, 0.f};

#pragma unroll
  for (int kk = 0; kk < 8; kk++) {
    short8 bh[2], bl2[2];
#pragma unroll
    for (int nt = 0; nt < 2; nt++) {
      int n = w * 32 + nt * 16 + m16;
      size_t off = (size_t)kk * 8192 + (size_t)n * 32 + (size_t)(((q + (n >> 1)) & 3) * 8);
      bh[nt] = *(const short8*)(Whi + off);
      bl2[nt] = *(const short8*)(Wlo + off);
    }
#pragma unroll
    for (int mt = 0; mt < 2; mt++) {
      int row = mt * 16 + m16;
      int abase = (row >> 2) * REG16 + (row & 3) * 264 + kk * 32 + q * 8;
      short8 ah = *(const short8*)&AB[abase];
      short8 al2 = *(const short8*)&AB[abase + 1056];
#pragma unroll
      for (int nt = 0; nt < 2; nt++) {
        acc[mt][nt] = __builtin_amdgcn_mfma_f32_16x16x32_bf16(ah, bh[nt], acc[mt][nt], 0, 0, 0);
        acc[mt][nt] = __builtin_amdgcn_mfma_f32_16x16x32_bf16(al2, bh[nt], acc[mt][nt], 0, 0, 0);
        acc[mt][nt] = __builtin_amdgcn_mfma_f32_16x16x32_bf16(ah, bl2[nt], acc[mt][nt], 0, 0, 0);
      }
    }
  }

  if constexpr (DK) {
    // acc = silu(acc + b1[col]) in-registers, then second K-loop (A1 @ W1) on top
#pragma unroll
    for (int mt = 0; mt < 2; mt++)
#pragma unroll
      for (int nt = 0; nt < 2; nt++) {
        int col = w * 32 + nt * 16 + m16;
        float bp = b1[col];
#pragma unroll
        for (int r = 0; r < 4; r++) {
          float t2 = acc[mt][nt][r] + bp;
          acc[mt][nt][r] = t2 / (1.f + __expf(-t2));
        }
      }
    __syncthreads();  // all waves done reading A from loop 1
    {
      const u16* Ahp = A1 + (size_t)b * MSZ;
      const u16* Alp = Ahp + aLo;
      int s = tid;
      int r = s >> 4;
      int c = (s & 15) << 4;
      size_t ao = (size_t)(bm + r) * 256 + c;
      int base = (r >> 2) * REG16 + (r & 3) * 264 + c;
      *(uint4*)&AB[base] = *(const uint4*)(Ahp + ao);
      *(uint4*)&AB[base + 8] = *(const uint4*)(Ahp + ao + 8);
      *(uint4*)&AB[base + 1056] = *(const uint4*)(Alp + ao);
      *(uint4*)&AB[base + 1056 + 8] = *(const uint4*)(Alp + ao + 8);
    }
    __syncthreads();
    const u16* W1h = W1;
    const u16* W1l = W1 + wLo;
#pragma unroll
    for (int kk = 0; kk < 8; kk++) {
      short8 bh[2], bl2[2];
#pragma unroll
      for (int nt = 0; nt < 2; nt++) {
        int n = w * 32 + nt * 16 + m16;
        size_t off = (size_t)kk * 8192 + (size_t)n * 32 + (size_t)(((q + (n >> 1)) & 3) * 8);
        bh[nt] = *(const short8*)(W1h + off);
        bl2[nt] = *(const short8*)(W1l + off);
      }
#pragma unroll
      for (int mt = 0; mt < 2; mt++) {
        int row = mt * 16 + m16;
        int abase = (row >> 2) * REG16 + (row & 3) * 264 + kk * 32 + q * 8;
        short8 ah = *(const short8*)&AB[abase];
        short8 al2 = *(const short8*)&AB[abase + 1056];
#pragma unroll
        for (int nt = 0; nt < 2; nt++) {
          acc[mt][nt] = __builtin_amdgcn_mfma_f32_16x16x32_bf16(ah, bh[nt], acc[mt][nt], 0, 0, 0);
          acc[mt][nt] = __builtin_amdgcn_mfma_f32_16x16x32_bf16(al2, bh[nt], acc[mt][nt], 0, 0, 0);
          acc[mt][nt] = __builtin_amdgcn_mfma_f32_16x16x32_bf16(ah, bl2[nt], acc[mt][nt], 0, 0, 0);
        }
      }
    }
  }

  if (NG == 1 || chain == 0)
    gemm_epi<F0>(acc, b, bm, w, m16, q, b0, mask, xf32, gma, bta, bmu, bvr, addt, o0, oLo);
  else if (chain == 1)
    gemm_epi<F1>(acc, b, bm, w, m16, q, b1, mask, xf32, gma, bta, bmu, bvr, addt, o1, oLo);
  else
    gemm_epi<F2>(acc, b, bm, w, m16, q, b2, mask, xf32, gma, bta, bmu, bvr, addt, o2, oLo);
}

// ---------------------------------------------------------------------------
// kv[d][e] = sum_n pk[n][d] * pv[n][e], from transposed bf16 hi/lo planes.
// LDS-free, 3-term. Split-K=8: part[z = p*8+b][d][e], grid (2,2,64).
// ---------------------------------------------------------------------------
__global__ __launch_bounds__(256, 2) void kv_k(
    const u16* __restrict__ pkT, const u16* __restrict__ pvT, float* __restrict__ part)
{
  int et = blockIdx.x * 128;
  int dt = blockIdx.y * 128;
  int z = blockIdx.z;
  int b = z & 7;
  int p = z >> 3;
  int tid = threadIdx.x;
  int lane = tid & 63, w = tid >> 6;
  int m16 = lane & 15, q = lane >> 4;

  const u16* pkh = pkT + (size_t)b * TP_MAT;
  const u16* pkl = pkh + TP_LO;
  const u16* pvh = pvT + (size_t)b * TP_MAT;
  const u16* pvl = pvh + TP_LO;

  int d_base = dt + (w >> 1) * 64 + m16;
  int e_base = et + (w & 1) * 64 + m16;

  floatx4 acc[4][4];
#pragma unroll
  for (int i = 0; i < 4; i++)
#pragma unroll
    for (int j = 0; j < 4; j++) acc[i][j] = (floatx4){0.f, 0.f, 0.f, 0.f};

#pragma unroll
  for (int kt = 0; kt < 8; kt++) {
    int kc = p * 256 + kt * 32 + q * 8;
    short8 ah[4], al[4], bh[4], bl[4];
#pragma unroll
    for (int mt = 0; mt < 4; mt++) {
      size_t o = (size_t)(d_base + mt * 16) * 2048 + kc;
      ah[mt] = *(const short8*)(pkh + o);
      al[mt] = *(const short8*)(pkl + o);
    }
#pragma unroll
    for (int nt = 0; nt < 4; nt++) {
      size_t o = (size_t)(e_base + nt * 16) * 2048 + kc;
      bh[nt] = *(const short8*)(pvh + o);
      bl[nt] = *(const short8*)(pvl + o);
    }
#pragma unroll
    for (int mt = 0; mt < 4; mt++)
#pragma unroll
      for (int nt = 0; nt < 4; nt++) {
        acc[mt][nt] = __builtin_amdgcn_mfma_f32_16x16x32_bf16(ah[mt], bh[nt], acc[mt][nt], 0, 0, 0);
        acc[mt][nt] = __builtin_amdgcn_mfma_f32_16x16x32_bf16(al[mt], bh[nt], acc[mt][nt], 0, 0, 0);
        acc[mt][nt] = __builtin_amdgcn_mfma_f32_16x16x32_bf16(ah[mt], bl[nt], acc[mt][nt], 0, 0, 0);
      }
  }

#pragma unroll
  for (int mt = 0; mt < 4; mt++)
#pragma unroll
    for (int r = 0; r < 4; r++) {
      int d = dt + (w >> 1) * 64 + mt * 16 + q * 4 + r;
#pragma unroll
      for (int nt = 0; nt < 4; nt++) {
        int e = et + (w & 1) * 64 + nt * 16 + m16;
        part[(size_t)z * 65536 + (size_t)d * 256 + e] = acc[mt][nt][r];
      }
    }
}

// Reduce split-K partials (8 p-planes) and emit kv bf16 hi/lo swizzled planes.
__global__ __launch_bounds__(256) void kv_conv_k(const float* __restrict__ part, u16* __restrict__ dst)
{
  int gid = blockIdx.x * 256 + threadIdx.x;  // 8 * 8192 = 65536
  int b = gid >> 13;
  int rem = gid & 8191;
  int kb = rem >> 10;
  int e = (rem >> 2) & 255;
  int slot = rem & 3;
  int qv = (slot - (e >> 1)) & 3;
  int d0 = kb * 32 + qv * 8;
  const float* src = part + (size_t)b * 65536 + (size_t)d0 * 256 + e;
  u32 oh[4], ol[4];
#pragma unroll
  for (int t2 = 0; t2 < 4; t2++) {
    float s0 = 0.f, s1 = 0.f;
#pragma unroll
    for (int pp = 0; pp < 8; pp++) {
      const float* sp = src + (size_t)pp * 524288 + t2 * 512;
      s0 += sp[0];
      s1 += sp[256];
    }
    u16 h0, l0, h1, l1;
    splitbf(s0, h0, l0);
    splitbf(s1, h1, l1);
    oh[t2] = (u32)h0 | ((u32)h1 << 16);
    ol[t2] = (u32)l0 | ((u32)l1 << 16);
  }
  uint4 qh; qh.x = oh[0]; qh.y = oh[1]; qh.z = oh[2]; qh.w = oh[3];
  uint4 ql; ql.x = ol[0]; ql.y = ol[1]; ql.z = ol[2]; ql.w = ol[3];
  *(uint4*)(dst + (size_t)gid * 8) = qh;
  *(uint4*)(dst + 524288 + (size_t)gid * 8) = ql;
}

// ---------------------------------------------------------------------------
extern "C" void kernel_launch(void* const* d_in, const int* in_sizes, int n_in,
                              void* d_out, int out_size, void* d_ws, size_t ws_size,
                              hipStream_t stream)
{
  const float* x = (const float*)d_in[0];
  const float* adj = (const float*)d_in[1];
  const float* mask = (const float*)d_in[2];
  const float* W_lin = (const float*)d_in[3];
  const float* b_lin = (const float*)d_in[4];
  const float* Wq_mp = (const float*)d_in[5];
  const float* bq_mp = (const float*)d_in[6];
  const float* Wk_mp = (const float*)d_in[7];
  const float* bk_mp = (const float*)d_in[8];
  const float* Wv_mp = (const float*)d_in[9];
  const float* bv_mp = (const float*)d_in[10];
  const float* Wk_att = (const float*)d_in[11];
  const float* Wv_att = (const float*)d_in[12];
  const float* Wq_att = (const float*)d_in[13];
  const float* Wo_att = (const float*)d_in[14];
  const float* bn_gamma = (const float*)d_in[15];
  const float* bn_beta = (const float*)d_in[16];
  const float* bn_mean = (const float*)d_in[17];
  const float* bn_var = (const float*)d_in[18];
  const float* W_proj = (const float*)d_in[19];
  const float* b_proj = (const float*)d_in[20];
  const float* W_res = (const float*)d_in[21];
  const float* b_res = (const float*)d_in[22];

  char* ws = (char*)d_ws;
  int* CNT    = (int*)(ws + 0);                 // 64 KB
  int* IDX    = (int*)(ws + (1ull << 20));      // 4 MB
  u16* WSZ    = (u16*)(ws + (5ull << 20));      // 4 MB (bf16 hi 2MB + lo 2MB)
  u16* KVS    = (u16*)(ws + (9ull << 20));      // 2 MB
  float* KVP  = (float*)(ws + (11ull << 20));   // 16 MB
  u16* XHL    = (u16*)(ws + (27ull << 20));     // 16 MB (8 hi + 8 lo)
  u16* HHL    = (u16*)(ws + (43ull << 20));     // 16 MB (8 hi + 8 lo)
  float* GA   = (float*)(ws + (59ull << 20));   // 50.4 MB fp32 (24 gapped mats)
  float* GB   = (float*)(ws + (110ull << 20));  // 50.4 MB fp32 (ping-pong)
  u16* PKT    = (u16*)(ws + (161ull << 20));    // 16 MB
  u16* PVT    = (u16*)(ws + (177ull << 20));    // 16 MB
  u16* ATT    = (u16*)(ws + (193ull << 20));    // 16 MB
  u16* YHL    = (u16*)(ws + (209ull << 20));    // 16 MB
  u16* PQHL   = (u16*)(ws + (225ull << 20));    // 16 MB -> total 241 MB

  const size_t WLO = 1048576;   // weight lo-plane offset (u16 elems)
  const size_t KLO = 524288;    // kv lo-plane offset
  const size_t A8  = 8 * MSZ;   // lo offset for 8-mat hi/lo buffers
  const unsigned FG = F_GSTRIDE;  // G-output epi flags (plain stores)

  // --- prologue: weight conv + x conv + neighbor lists + G gap zero ---
  WPtrs wp;
  wp.p[0] = W_lin;
  wp.p[1] = Wq_mp; wp.p[2] = Wq_mp + 65536; wp.p[3] = Wq_mp + 131072;
  wp.p[4] = Wk_mp; wp.p[5] = Wk_mp + 65536; wp.p[6] = Wk_mp + 131072;
  wp.p[7] = Wv_mp; wp.p[8] = Wv_mp + 65536; wp.p[9] = Wv_mp + 131072;
  wp.p[10] = Wk_att; wp.p[11] = Wv_att; wp.p[12] = Wq_att; wp.p[13] = Wo_att;
  wp.p[14] = W_proj; wp.p[15] = W_res;
  prologue_k<<<21040, 256, 0, stream>>>(wp, WSZ, x, XHL, A8, adj, CNT, IDX, GA, GB);

  // --- h = x @ W_lin + b_lin -> hi/lo planes ---
  gemm_k<1, 0u, F_BIAS | F_OUTHL, 0u, 0u><<<512, 512, 0, stream>>>(
      XHL, XHL, XHL, A8, WSZ, WSZ, WSZ, WLO,
      b_lin, nullptr, nullptr, mask, nullptr,
      bn_gamma, bn_beta, bn_mean, bn_var, nullptr,
      HHL, nullptr, nullptr, A8,
      nullptr, nullptr, nullptr, nullptr, CNT, IDX);

  // --- mp step 0: G0 = h @ W[0] (dense copy staging, gapped out) ---
  gemm_k<3, 0u, FG, FG, FG><<<1536, 512, 0, stream>>>(
      HHL, HHL, HHL, A8,
      WSZ + (size_t)1 * 65536, WSZ + (size_t)4 * 65536, WSZ + (size_t)7 * 65536, WLO,
      nullptr, nullptr, nullptr, mask, nullptr,
      bn_gamma, bn_beta, bn_mean, bn_var, nullptr,
      GA + 256, GA + 8 * GSTR + 256, GA + 16 * GSTR + 256, 0,
      nullptr, nullptr, nullptr, nullptr, CNT, IDX);

  // --- mp steps 1..5: fused-agg staging (A = silu(agg(G_prev)+b)), G ping-pong
  for (int s = 1; s < 6; s++) {
    int iw = s >> 1;            // weight index for this step
    int ib = (s - 1) >> 1;      // bias index of the fused agg (prev step)
    float* Gin = (s & 1) ? GA : GB;
    float* Gout = (s & 1) ? GB : GA;
    gemm_k<3, F_BIAS | F_SILU, FG, FG, FG><<<1536, 512, 0, stream>>>(
        nullptr, nullptr, nullptr, 0,
        WSZ + (size_t)(1 + iw) * 65536, WSZ + (size_t)(4 + iw) * 65536,
        WSZ + (size_t)(7 + iw) * 65536, WLO,
        nullptr, nullptr, nullptr, mask, nullptr,
        bn_gamma, bn_beta, bn_mean, bn_var, nullptr,
        Gout + 256, Gout + 8 * GSTR + 256, Gout + 16 * GSTR + 256, 0,
        Gin, bq_mp + ib * 256, bk_mp + ib * 256, bv_mp + ib * 256, CNT, IDX);
  }
  // G_5 lives in GB (s=5 wrote GB)

  // --- attention projections, fused final-agg staging + (pq | pk | pv) epis ---
  gemm_k<3, F_BIAS | F_SILU | F_MASKPOST,
         F_OUTHL, F_SILU | F_MASKPRE | F_TPLANES, F_MASKPOST | F_TPLANES>
      <<<1536, 512, 0, stream>>>(
      nullptr, nullptr, nullptr, 0,
      WSZ + (size_t)12 * 65536, WSZ + (size_t)10 * 65536, WSZ + (size_t)11 * 65536, WLO,
      nullptr, nullptr, nullptr, mask, nullptr,
      bn_gamma, bn_beta, bn_mean, bn_var, nullptr,
      PQHL, PKT, PVT, A8,
      GB, bq_mp + 512, bk_mp + 512, bv_mp + 512, CNT, IDX);

  // --- kv = pk^T pv ---
  kv_k<<<dim3(2, 2, 64), 256, 0, stream>>>(PKT, PVT, KVP);
  kv_conv_k<<<256, 256, 0, stream>>>(KVP, KVS);

  // --- attn = pq @ kv -> hi/lo ---
  gemm_k<1, 0u, F_BPERMAT | F_OUTHL, 0u, 0u><<<512, 512, 0, stream>>>(
      PQHL, PQHL, PQHL, A8, KVS, KVS, KVS, KLO,
      nullptr, nullptr, nullptr, mask, nullptr,
      bn_gamma, bn_beta, bn_mean, bn_var, nullptr,
      ATT, nullptr, nullptr, A8,
      nullptr, nullptr, nullptr, nullptr, CNT, IDX);

  // --- y = BN(attn @ Wo + x) -> hi/lo ---
  gemm_k<1, 0u, F_ADDX | F_BN | F_OUTHL, 0u, 0u><<<512, 512, 0, stream>>>(
      ATT, ATT, ATT, A8,
      WSZ + (size_t)13 * 65536, nullptr, nullptr, WLO,
      nullptr, nullptr, nullptr, mask, x,
      bn_gamma, bn_beta, bn_mean, bn_var, nullptr,
      YHL, nullptr, nullptr, A8,
      nullptr, nullptr, nullptr, nullptr, CNT, IDX);

  // --- out = (silu(y @ W_proj + b_proj) + x @ W_res + b_res) * mask, dual-K ---
  gemm_k<1, 0u, F_BIAS | F_MASKPOST, 0u, 0u, true><<<512, 512, 0, stream>>>(
      YHL, XHL, YHL, A8,
      WSZ + (size_t)14 * 65536, WSZ + (size_t)15 * 65536, nullptr, WLO,
      b_res, b_proj, nullptr, mask, nullptr,
      bn_gamma, bn_beta, bn_mean, bn_var, nullptr,
      d_out, nullptr, nullptr, 0,
      nullptr, nullptr, nullptr, nullptr, CNT, IDX);

  (void)in_sizes; (void)n_in; (void)out_size; (void)ws_size;
}

// Round 12
// 762.309 us; speedup vs baseline: 1.3004x; 1.1013x over previous
//
#include <hip/hip_runtime.h>
#include <stdint.h>

#define NB 8
#define NN 2048
#define NU 256
#define CAP 64
#define BNEPS 0.001f
#define GSTR ((size_t)(NN * NU + 256))   // G mat stride in floats (256-float zero gap BEFORE each mat)

typedef __attribute__((ext_vector_type(8))) short short8;
typedef __attribute__((ext_vector_type(4))) float floatx4;
typedef unsigned short u16;
typedef unsigned int u32;

__device__ __forceinline__ float bf2f(u16 u) {
  union { u32 i; float f; } c; c.i = ((u32)u) << 16; return c.f;
}
__device__ __forceinline__ u16 f2bf(float f) {
  union { float f; u32 i; } c; c.f = f;
  return (u16)((c.i + 0x7fffu + ((c.i >> 16) & 1u)) >> 16);
}
// bf16 hi/lo split: a = bf2f(h) + bf2f(l) + O(2^-18 |a|)
__device__ __forceinline__ void splitbf(float a, u16& h, u16& l) {
  h = f2bf(a);
  l = f2bf(a - bf2f(h));
}

enum : unsigned {
  F_BIAS = 2u, F_SILU = 4u, F_MASKPRE = 8u, F_MASKPOST = 16u,
  F_ADDX = 32u, F_BN = 64u, F_ADDT = 128u, F_BPERMAT = 512u,
  F_TPLANES = 1024u, F_OUTHL = 2048u, F_GSTRIDE = 8192u
};

#define TP_MAT 524288   // per-batch transposed plane: 256 cols x 2048 rows (u16)
#define TP_LO  4194304  // transposed lo plane offset (u16 elems)
#define MSZ ((size_t)NN * NU)

struct WPtrs { const float* p[16]; };

// ---------------------------------------------------------------------------
// Merged prologue: [0,512) weight conv, [512,4608) x conv, [4608,20992) nbr
// (pads idx rows to CAP with -1), [20992,21040) zero the G mat gaps.
// ---------------------------------------------------------------------------
__global__ __launch_bounds__(256) void prologue_k(
    WPtrs wp, u16* __restrict__ wdst,
    const float* __restrict__ x, u16* __restrict__ xdst, size_t xLo,
    const float* __restrict__ adj, int* __restrict__ cnt, int* __restrict__ idx,
    float* __restrict__ ga, float* __restrict__ gb)
{
  int bid = blockIdx.x;
  int tid = threadIdx.x;
  __shared__ int c0;
  if (bid < 512) {
    // weight conversion: f32 [K=256][N=256] -> TWO bf16 swizzled-B^T planes
    int gid = bid * 256 + tid;  // 16 mats * 8192 chunks
    int mat = gid >> 13;
    int rem = gid & 8191;
    int kb = rem >> 10;
    int n = (rem >> 2) & 255;
    int slot = rem & 3;
    int qv = (slot - (n >> 1)) & 3;
    int k0 = kb * 32 + qv * 8;
    const float* W = wp.p[mat];
    u32 oh[4], ol[4];
#pragma unroll
    for (int t2 = 0; t2 < 4; t2++) {
      float f0 = W[(size_t)(k0 + 2 * t2) * 256 + n];
      float f1 = W[(size_t)(k0 + 2 * t2 + 1) * 256 + n];
      u16 h0, l0, h1, l1;
      splitbf(f0, h0, l0);
      splitbf(f1, h1, l1);
      oh[t2] = (u32)h0 | ((u32)h1 << 16);
      ol[t2] = (u32)l0 | ((u32)l1 << 16);
    }
    uint4 qh; qh.x = oh[0]; qh.y = oh[1]; qh.z = oh[2]; qh.w = oh[3];
    uint4 ql; ql.x = ol[0]; ql.y = ol[1]; ql.z = ol[2]; ql.w = ol[3];
    *(uint4*)(wdst + (size_t)gid * 8) = qh;
    *(uint4*)(wdst + 1048576 + (size_t)gid * 8) = ql;
  } else if (bid < 4608) {
    // x conversion: fp32 -> row-major hi/lo bf16 planes
    size_t i = ((size_t)(bid - 512) * 256 + tid) * 4;
    float4 v = *(const float4*)(x + i);
    u16 h0, l0, h1, l1, h2, l2, h3, l3;
    splitbf(v.x, h0, l0); splitbf(v.y, h1, l1);
    splitbf(v.z, h2, l2); splitbf(v.w, h3, l3);
    uint2 H; H.x = (u32)h0 | ((u32)h1 << 16); H.y = (u32)h2 | ((u32)h3 << 16);
    uint2 L; L.x = (u32)l0 | ((u32)l1 << 16); L.y = (u32)l2 | ((u32)l3 << 16);
    *(uint2*)(xdst + i) = H;
    *(uint2*)(xdst + xLo + i) = L;
  } else if (bid < 20992) {
    // neighbor-list build: one block per (b,m) row of adj; values exactly 0/1
    int row = bid - 4608;
    const float* base = adj + (size_t)row * NN;
    if (tid == 0) c0 = 0;
    __syncthreads();
#pragma unroll
    for (int j = 0; j < 8; j++) {
      int n = j * 256 + tid;  // coalesced
      if (base[n] != 0.f) {
        int p = atomicAdd(&c0, 1);
        if (p < CAP) idx[(size_t)row * CAP + p] = n;
      }
    }
    __syncthreads();
    int cc = (c0 < CAP ? c0 : CAP);
    // pad to CAP with sentinel -1 (points at the zero gap before each G mat)
    for (int p = cc + tid; p < CAP; p += 256) idx[(size_t)row * CAP + p] = -1;
    if (tid == 0) cnt[row] = cc;
  } else {
    // zero the 256-float gap before each of the 24 mats in GA and GB
    int g = bid - 20992;           // 0..47
    float* base = (g < 24 ? ga : gb) + (size_t)(g % 24) * GSTR;
    base[tid] = 0.f;
  }
}

// ---------------------------------------------------------------------------
// Per-chain epilogue (compile-time flags). Wave layout: 32 rows x 32 cols
// (mt=2 row tiles, nt=2 col tiles), wave w owns cols [w*32, w*32+32).
// F_GSTRIDE: fp32 out with per-b stride GSTR (gapped G layout). Plain stores
// everywhere (NT stores amplify writes 2-3x on gfx950 — R3/R10 lesson).
// ---------------------------------------------------------------------------
template <unsigned F>
__device__ __forceinline__ void gemm_epi(
    floatx4 (&acc)[2][2], int b, int bm, int w, int m16, int q,
    const float* __restrict__ bias, const float* __restrict__ mask,
    const float* __restrict__ xf32,
    const float* __restrict__ gma, const float* __restrict__ bta,
    const float* __restrict__ bmu, const float* __restrict__ bvr,
    const float* __restrict__ addt, void* __restrict__ outp, size_t oLo)
{
#pragma unroll
  for (int mt = 0; mt < 2; mt++) {
    if (F & F_TPLANES) {
      u16* oh = (u16*)outp + (size_t)b * TP_MAT;
      u16* ol = oh + TP_LO;
      int gr0 = bm + mt * 16 + q * 4;
#pragma unroll
      for (int nt = 0; nt < 2; nt++) {
        int col = w * 32 + nt * 16 + m16;
        u16 hh[4], ll[4];
#pragma unroll
        for (int r = 0; r < 4; r++) {
          float t2 = acc[mt][nt][r];
          float mv = mask[b * NN + gr0 + r];
          if (F & F_MASKPRE) t2 *= mv;
          if (F & F_SILU) t2 = t2 / (1.f + __expf(-t2));
          if (F & F_MASKPOST) t2 *= mv;
          splitbf(t2, hh[r], ll[r]);
        }
        uint2 H2, L2v;
        H2.x = (u32)hh[0] | ((u32)hh[1] << 16);
        H2.y = (u32)hh[2] | ((u32)hh[3] << 16);
        L2v.x = (u32)ll[0] | ((u32)ll[1] << 16);
        L2v.y = (u32)ll[2] | ((u32)ll[3] << 16);
        *(uint2*)(oh + (size_t)col * 2048 + gr0) = H2;
        *(uint2*)(ol + (size_t)col * 2048 + gr0) = L2v;
      }
    } else {
#pragma unroll
      for (int r = 0; r < 4; r++) {
        int gr = bm + mt * 16 + q * 4 + r;
        float mval = 1.f;
        if (F & (F_MASKPRE | F_MASKPOST)) mval = mask[b * NN + gr];
#pragma unroll
        for (int nt = 0; nt < 2; nt++) {
          int col = w * 32 + nt * 16 + m16;
          float t2 = acc[mt][nt][r];
          if (F & F_BIAS) t2 += bias[col];
          if (F & F_MASKPRE) t2 *= mval;
          if (F & F_SILU) t2 = t2 / (1.f + __expf(-t2));
          if (F & F_ADDX) t2 += xf32[((size_t)b * NN + gr) * NU + col];
          if (F & F_BN) t2 = gma[col] * (t2 - bmu[col]) * rsqrtf(bvr[col] + BNEPS) + bta[col];
          if (F & F_ADDT) t2 += addt[((size_t)b * NN + gr) * NU + col];
          if (F & F_MASKPOST) t2 *= mval;
          size_t o;
          if (F & F_GSTRIDE) o = (size_t)b * GSTR + (size_t)gr * NU + col;
          else o = ((size_t)b * NN + gr) * NU + col;
          if (F & F_OUTHL) {
            u16 h0, l0;
            splitbf(t2, h0, l0);
            ((u16*)outp)[o] = h0;
            ((u16*)outp)[o + oLo] = l0;
          } else {
            ((float*)outp)[o] = t2;
          }
        }
      }
    }
  }
}

// ---------------------------------------------------------------------------
// Dense GEMM, fp32-emulated via bf16 hi/lo 3-term MFMA. Up to 3 fused chains.
// Tile 32 rows x 256 cols, 512 thr = 8 waves, each 32x32 (B unique per wave).
// LDS PADDED TO 56 KB (residency control, R12): only 2 blocks fit per CU, so
// only 512 blocks are resident machine-wide = exactly ONE chain's blocks
// (grid 1536 chain-major). Per-XCD L2 working set drops from ~9 MB (2 chains)
// to ~5 MB (1 chain: G-in 2 + G-out dirty 2 + W 0.5) -> the 16x G-in row
// reuse is served by L2 (34.5 TB/s) instead of L3 (~10.7 TB/s observed).
// Occupancy cost: 32 -> 16 waves/CU (R4 measured that at ~2 us).
// A-staging modes (compile-time SF):
//   SF == 0 : A pre-split hi/lo planes, pure-copy staged to LDS.
//   SF != 0 : FUSED AGGREGATION staging — branchy interleaved exact gather
//             (best measured variant, R2): 4 rows/wave, wave-uniform count
//             predicates, float4 loads, bit-identical sum order.
// DK : dual-K mode (NG==1): after chain-0 K-loop, acc = silu(acc + b1[col]),
//      restage A from A1, second K-loop with W1 accumulating.
// B: per-lane fragments straight from swizzled global planes (L2-hot).
// Grid 1-D, xcd = id&7. NG==3 grid 1536, chain-major (t>>6), 64 tiles/chain.
// NOTE: cross-dispatch L2 reuse impossible (dispatch-boundary release/acquire,
// non-coherent per-XCD L2s) — R5/R6. NT stores banned — R3/R10. DMA
// global_load_lds gather triples HBM traffic — R11.
// ---------------------------------------------------------------------------
#define LDSPAD_U16 28672   // 57344 B total: 160KB/56KB = 2 blocks/CU

template <int NG, unsigned SF, unsigned F0, unsigned F1, unsigned F2, bool DK = false>
__global__ __launch_bounds__(512, 8) void gemm_k(
    const u16* __restrict__ A0, const u16* __restrict__ A1, const u16* __restrict__ A2,
    size_t aLo,
    const u16* __restrict__ W0, const u16* __restrict__ W1, const u16* __restrict__ W2,
    size_t wLo,
    const float* __restrict__ b0, const float* __restrict__ b1, const float* __restrict__ b2,
    const float* __restrict__ mask,
    const float* __restrict__ xf32,
    const float* __restrict__ gma, const float* __restrict__ bta,
    const float* __restrict__ bmu, const float* __restrict__ bvr,
    const float* __restrict__ addt,
    void* __restrict__ o0, void* __restrict__ o1, void* __restrict__ o2,
    size_t oLo,
    const float* __restrict__ gsrc,
    const float* __restrict__ sb0, const float* __restrict__ sb1, const float* __restrict__ sb2,
    const int* __restrict__ ncnt, const int* __restrict__ nidx)
{
  const int tid = threadIdx.x;
  const int id = blockIdx.x;
  const int xcd = id & 7;
  const int t = id >> 3;
  const int chain = (NG == 1) ? 0 : (t >> 6);   // chain-major: 64 tiles/chain
  const int xt = (NG == 1) ? t : (t & 63);
  const int b = xcd;
  const int bm = xt * 32;

  // Ah at [0, 8448), Al at [8448, 16896); rest of the array is residency pad.
  __shared__ alignas(16) u16 AB[LDSPAD_U16];
  u16* const Ah = AB;
  u16* const Al = AB + 32 * 264;

  const u16* Wsel = (chain == 0) ? W0 : (chain == 1 ? W1 : W2);
  if (F0 & F_BPERMAT) Wsel = W0 + (size_t)b * 65536;  // NG==1 only
  const u16* Whi = Wsel;
  const u16* Wlo = Whi + wLo;

  const int lane = tid & 63;
  const int w = tid >> 6;      // 8 waves, each owns 32 cols

  if constexpr (SF != 0u) {
    // ---- fused-agg staging: wave wv computes rows wv*4 .. wv*4+3,
    //      branchy interleaved exact gather across the 4 rows (R2) ----
    const float* __restrict__ gm = gsrc + (size_t)(chain * 8 + b) * GSTR + 256;
    const float* sb = (chain == 0) ? sb0 : (chain == 1 ? sb1 : sb2);
    const int c = lane * 4;
    float4 bb = *(const float4*)(sb + c);
    const int r0 = w * 4;
    int cnts[4];
    const int* ips[4];
    float4 av[4];
    int rowids[4];
#pragma unroll
    for (int i = 0; i < 4; i++) {
      rowids[i] = b * NN + bm + r0 + i;
      cnts[i] = ncnt[rowids[i]];
      ips[i] = nidx + (size_t)rowids[i] * CAP;
      av[i].x = av[i].y = av[i].z = av[i].w = 0.f;
    }
    int maxc = cnts[0];
    maxc = cnts[1] > maxc ? cnts[1] : maxc;
    maxc = cnts[2] > maxc ? cnts[2] : maxc;
    maxc = cnts[3] > maxc ? cnts[3] : maxc;
    for (int e = 0; e + 4 <= maxc; e += 4) {
#pragma unroll
      for (int i = 0; i < 4; i++) {
        if (e + 4 <= cnts[i]) {  // wave-uniform
          int4 i4 = *(const int4*)(ips[i] + e);
          float4 v0 = *(const float4*)(gm + ((size_t)i4.x << 8) + c);
          float4 v1 = *(const float4*)(gm + ((size_t)i4.y << 8) + c);
          float4 v2 = *(const float4*)(gm + ((size_t)i4.z << 8) + c);
          float4 v3 = *(const float4*)(gm + ((size_t)i4.w << 8) + c);
          av[i].x += v0.x + v1.x + v2.x + v3.x;
          av[i].y += v0.y + v1.y + v2.y + v3.y;
          av[i].z += v0.z + v1.z + v2.z + v3.z;
          av[i].w += v0.w + v1.w + v2.w + v3.w;
        }
      }
    }
#pragma unroll
    for (int i = 0; i < 4; i++) {
      for (int e = cnts[i] & ~3; e < cnts[i]; e++) {
        float4 v = *(const float4*)(gm + ((size_t)ips[i][e] << 8) + c);
        av[i].x += v.x; av[i].y += v.y; av[i].z += v.z; av[i].w += v.w;
      }
    }
#pragma unroll
    for (int i = 0; i < 4; i++) {
      float ov[4] = {av[i].x + bb.x, av[i].y + bb.y, av[i].z + bb.z, av[i].w + bb.w};
      float mv = (SF & F_MASKPOST) ? mask[rowids[i]] : 1.f;
      u16 hh[4], ll[4];
#pragma unroll
      for (int j = 0; j < 4; j++) {
        float t2 = ov[j];
        if (SF & F_SILU) t2 = t2 / (1.f + __expf(-t2));
        if (SF & F_MASKPOST) t2 *= mv;
        splitbf(t2, hh[j], ll[j]);
      }
      uint2 H; H.x = (u32)hh[0] | ((u32)hh[1] << 16); H.y = (u32)hh[2] | ((u32)hh[3] << 16);
      uint2 L; L.x = (u32)ll[0] | ((u32)ll[1] << 16); L.y = (u32)ll[2] | ((u32)ll[3] << 16);
      *(uint2*)&Ah[(r0 + i) * 264 + c] = H;
      *(uint2*)&Al[(r0 + i) * 264 + c] = L;
    }
  } else {
    // ---- copy staging from pre-split hi/lo planes (32 x 256) ----
    const u16* Abase = (chain == 0) ? A0 : (chain == 1 ? A1 : A2);
    const u16* Ahp = Abase + (size_t)b * MSZ;
    const u16* Alp = Ahp + aLo;
    {
      int s = tid;
      int r = s >> 4;
      int c = (s & 15) << 4;
      size_t ao = (size_t)(bm + r) * 256 + c;
      *(uint4*)&Ah[r * 264 + c] = *(const uint4*)(Ahp + ao);
      *(uint4*)&Ah[r * 264 + c + 8] = *(const uint4*)(Ahp + ao + 8);
      *(uint4*)&Al[r * 264 + c] = *(const uint4*)(Alp + ao);
      *(uint4*)&Al[r * 264 + c + 8] = *(const uint4*)(Alp + ao + 8);
    }
  }
  __syncthreads();

  const int m16 = lane & 15;
  const int q = lane >> 4;

  floatx4 acc[2][2];
#pragma unroll
  for (int i = 0; i < 2; i++)
#pragma unroll
    for (int j = 0; j < 2; j++) acc[i][j] = (floatx4){0.f, 0.f, 0.f, 0.f};

#pragma unroll
  for (int kk = 0; kk < 8; kk++) {
    short8 bh[2], bl2[2];
#pragma unroll
    for (int nt = 0; nt < 2; nt++) {
      int n = w * 32 + nt * 16 + m16;
      size_t off = (size_t)kk * 8192 + (size_t)n * 32 + (size_t)(((q + (n >> 1)) & 3) * 8);
      bh[nt] = *(const short8*)(Whi + off);
      bl2[nt] = *(const short8*)(Wlo + off);
    }
#pragma unroll
    for (int mt = 0; mt < 2; mt++) {
      int row = mt * 16 + m16;
      short8 ah = *(const short8*)&Ah[row * 264 + kk * 32 + q * 8];
      short8 al2 = *(const short8*)&Al[row * 264 + kk * 32 + q * 8];
#pragma unroll
      for (int nt = 0; nt < 2; nt++) {
        acc[mt][nt] = __builtin_amdgcn_mfma_f32_16x16x32_bf16(ah, bh[nt], acc[mt][nt], 0, 0, 0);
        acc[mt][nt] = __builtin_amdgcn_mfma_f32_16x16x32_bf16(al2, bh[nt], acc[mt][nt], 0, 0, 0);
        acc[mt][nt] = __builtin_amdgcn_mfma_f32_16x16x32_bf16(ah, bl2[nt], acc[mt][nt], 0, 0, 0);
      }
    }
  }

  if constexpr (DK) {
    // acc = silu(acc + b1[col]) in-registers, then second K-loop (A1 @ W1) on top
#pragma unroll
    for (int mt = 0; mt < 2; mt++)
#pragma unroll
      for (int nt = 0; nt < 2; nt++) {
        int col = w * 32 + nt * 16 + m16;
        float bp = b1[col];
#pragma unroll
        for (int r = 0; r < 4; r++) {
          float t2 = acc[mt][nt][r] + bp;
          acc[mt][nt][r] = t2 / (1.f + __expf(-t2));
        }
      }
    __syncthreads();  // all waves done reading Ah/Al from loop 1
    {
      const u16* Ahp = A1 + (size_t)b * MSZ;
      const u16* Alp = Ahp + aLo;
      int s = tid;
      int r = s >> 4;
      int c = (s & 15) << 4;
      size_t ao = (size_t)(bm + r) * 256 + c;
      *(uint4*)&Ah[r * 264 + c] = *(const uint4*)(Ahp + ao);
      *(uint4*)&Ah[r * 264 + c + 8] = *(const uint4*)(Ahp + ao + 8);
      *(uint4*)&Al[r * 264 + c] = *(const uint4*)(Alp + ao);
      *(uint4*)&Al[r * 264 + c + 8] = *(const uint4*)(Alp + ao + 8);
    }
    __syncthreads();
    const u16* W1h = W1;
    const u16* W1l = W1 + wLo;
#pragma unroll
    for (int kk = 0; kk < 8; kk++) {
      short8 bh[2], bl2[2];
#pragma unroll
      for (int nt = 0; nt < 2; nt++) {
        int n = w * 32 + nt * 16 + m16;
        size_t off = (size_t)kk * 8192 + (size_t)n * 32 + (size_t)(((q + (n >> 1)) & 3) * 8);
        bh[nt] = *(const short8*)(W1h + off);
        bl2[nt] = *(const short8*)(W1l + off);
      }
#pragma unroll
      for (int mt = 0; mt < 2; mt++) {
        int row = mt * 16 + m16;
        short8 ah = *(const short8*)&Ah[row * 264 + kk * 32 + q * 8];
        short8 al2 = *(const short8*)&Al[row * 264 + kk * 32 + q * 8];
#pragma unroll
        for (int nt = 0; nt < 2; nt++) {
          acc[mt][nt] = __builtin_amdgcn_mfma_f32_16x16x32_bf16(ah, bh[nt], acc[mt][nt], 0, 0, 0);
          acc[mt][nt] = __builtin_amdgcn_mfma_f32_16x16x32_bf16(al2, bh[nt], acc[mt][nt], 0, 0, 0);
          acc[mt][nt] = __builtin_amdgcn_mfma_f32_16x16x32_bf16(ah, bl2[nt], acc[mt][nt], 0, 0, 0);
        }
      }
    }
  }

  if (NG == 1 || chain == 0)
    gemm_epi<F0>(acc, b, bm, w, m16, q, b0, mask, xf32, gma, bta, bmu, bvr, addt, o0, oLo);
  else if (chain == 1)
    gemm_epi<F1>(acc, b, bm, w, m16, q, b1, mask, xf32, gma, bta, bmu, bvr, addt, o1, oLo);
  else
    gemm_epi<F2>(acc, b, bm, w, m16, q, b2, mask, xf32, gma, bta, bmu, bvr, addt, o2, oLo);
}

// ---------------------------------------------------------------------------
// kv[d][e] = sum_n pk[n][d] * pv[n][e], from transposed bf16 hi/lo planes.
// LDS-free, 3-term. Split-K=8: part[z = p*8+b][d][e], grid (2,2,64).
// ---------------------------------------------------------------------------
__global__ __launch_bounds__(256, 2) void kv_k(
    const u16* __restrict__ pkT, const u16* __restrict__ pvT, float* __restrict__ part)
{
  int et = blockIdx.x * 128;
  int dt = blockIdx.y * 128;
  int z = blockIdx.z;
  int b = z & 7;
  int p = z >> 3;
  int tid = threadIdx.x;
  int lane = tid & 63, w = tid >> 6;
  int m16 = lane & 15, q = lane >> 4;

  const u16* pkh = pkT + (size_t)b * TP_MAT;
  const u16* pkl = pkh + TP_LO;
  const u16* pvh = pvT + (size_t)b * TP_MAT;
  const u16* pvl = pvh + TP_LO;

  int d_base = dt + (w >> 1) * 64 + m16;
  int e_base = et + (w & 1) * 64 + m16;

  floatx4 acc[4][4];
#pragma unroll
  for (int i = 0; i < 4; i++)
#pragma unroll
    for (int j = 0; j < 4; j++) acc[i][j] = (floatx4){0.f, 0.f, 0.f, 0.f};

#pragma unroll
  for (int kt = 0; kt < 8; kt++) {
    int kc = p * 256 + kt * 32 + q * 8;
    short8 ah[4], al[4], bh[4], bl[4];
#pragma unroll
    for (int mt = 0; mt < 4; mt++) {
      size_t o = (size_t)(d_base + mt * 16) * 2048 + kc;
      ah[mt] = *(const short8*)(pkh + o);
      al[mt] = *(const short8*)(pkl + o);
    }
#pragma unroll
    for (int nt = 0; nt < 4; nt++) {
      size_t o = (size_t)(e_base + nt * 16) * 2048 + kc;
      bh[nt] = *(const short8*)(pvh + o);
      bl[nt] = *(const short8*)(pvl + o);
    }
#pragma unroll
    for (int mt = 0; mt < 4; mt++)
#pragma unroll
      for (int nt = 0; nt < 4; nt++) {
        acc[mt][nt] = __builtin_amdgcn_mfma_f32_16x16x32_bf16(ah[mt], bh[nt], acc[mt][nt], 0, 0, 0);
        acc[mt][nt] = __builtin_amdgcn_mfma_f32_16x16x32_bf16(al[mt], bh[nt], acc[mt][nt], 0, 0, 0);
        acc[mt][nt] = __builtin_amdgcn_mfma_f32_16x16x32_bf16(ah[mt], bl[nt], acc[mt][nt], 0, 0, 0);
      }
  }

#pragma unroll
  for (int mt = 0; mt < 4; mt++)
#pragma unroll
    for (int r = 0; r < 4; r++) {
      int d = dt + (w >> 1) * 64 + mt * 16 + q * 4 + r;
#pragma unroll
      for (int nt = 0; nt < 4; nt++) {
        int e = et + (w & 1) * 64 + nt * 16 + m16;
        part[(size_t)z * 65536 + (size_t)d * 256 + e] = acc[mt][nt][r];
      }
    }
}

// Reduce split-K partials (8 p-planes) and emit kv bf16 hi/lo swizzled planes.
__global__ __launch_bounds__(256) void kv_conv_k(const float* __restrict__ part, u16* __restrict__ dst)
{
  int gid = blockIdx.x * 256 + threadIdx.x;  // 8 * 8192 = 65536
  int b = gid >> 13;
  int rem = gid & 8191;
  int kb = rem >> 10;
  int e = (rem >> 2) & 255;
  int slot = rem & 3;
  int qv = (slot - (e >> 1)) & 3;
  int d0 = kb * 32 + qv * 8;
  const float* src = part + (size_t)b * 65536 + (size_t)d0 * 256 + e;
  u32 oh[4], ol[4];
#pragma unroll
  for (int t2 = 0; t2 < 4; t2++) {
    float s0 = 0.f, s1 = 0.f;
#pragma unroll
    for (int pp = 0; pp < 8; pp++) {
      const float* sp = src + (size_t)pp * 524288 + t2 * 512;
      s0 += sp[0];
      s1 += sp[256];
    }
    u16 h0, l0, h1, l1;
    splitbf(s0, h0, l0);
    splitbf(s1, h1, l1);
    oh[t2] = (u32)h0 | ((u32)h1 << 16);
    ol[t2] = (u32)l0 | ((u32)l1 << 16);
  }
  uint4 qh; qh.x = oh[0]; qh.y = oh[1]; qh.z = oh[2]; qh.w = oh[3];
  uint4 ql; ql.x = ol[0]; ql.y = ol[1]; ql.z = ol[2]; ql.w = ol[3];
  *(uint4*)(dst + (size_t)gid * 8) = qh;
  *(uint4*)(dst + 524288 + (size_t)gid * 8) = ql;
}

// ---------------------------------------------------------------------------
extern "C" void kernel_launch(void* const* d_in, const int* in_sizes, int n_in,
                              void* d_out, int out_size, void* d_ws, size_t ws_size,
                              hipStream_t stream)
{
  const float* x = (const float*)d_in[0];
  const float* adj = (const float*)d_in[1];
  const float* mask = (const float*)d_in[2];
  const float* W_lin = (const float*)d_in[3];
  const float* b_lin = (const float*)d_in[4];
  const float* Wq_mp = (const float*)d_in[5];
  const float* bq_mp = (const float*)d_in[6];
  const float* Wk_mp = (const float*)d_in[7];
  const float* bk_mp = (const float*)d_in[8];
  const float* Wv_mp = (const float*)d_in[9];
  const float* bv_mp = (const float*)d_in[10];
  const float* Wk_att = (const float*)d_in[11];
  const float* Wv_att = (const float*)d_in[12];
  const float* Wq_att = (const float*)d_in[13];
  const float* Wo_att = (const float*)d_in[14];
  const float* bn_gamma = (const float*)d_in[15];
  const float* bn_beta = (const float*)d_in[16];
  const float* bn_mean = (const float*)d_in[17];
  const float* bn_var = (const float*)d_in[18];
  const float* W_proj = (const float*)d_in[19];
  const float* b_proj = (const float*)d_in[20];
  const float* W_res = (const float*)d_in[21];
  const float* b_res = (const float*)d_in[22];

  char* ws = (char*)d_ws;
  int* CNT    = (int*)(ws + 0);                 // 64 KB
  int* IDX    = (int*)(ws + (1ull << 20));      // 4 MB
  u16* WSZ    = (u16*)(ws + (5ull << 20));      // 4 MB (bf16 hi 2MB + lo 2MB)
  u16* KVS    = (u16*)(ws + (9ull << 20));      // 2 MB
  float* KVP  = (float*)(ws + (11ull << 20));   // 16 MB
  u16* XHL    = (u16*)(ws + (27ull << 20));     // 16 MB (8 hi + 8 lo)
  u16* HHL    = (u16*)(ws + (43ull << 20));     // 16 MB (8 hi + 8 lo)
  float* GA   = (float*)(ws + (59ull << 20));   // 50.4 MB fp32 (24 gapped mats)
  float* GB   = (float*)(ws + (110ull << 20));  // 50.4 MB fp32 (ping-pong)
  u16* PKT    = (u16*)(ws + (161ull << 20));    // 16 MB
  u16* PVT    = (u16*)(ws + (177ull << 20));    // 16 MB
  u16* ATT    = (u16*)(ws + (193ull << 20));    // 16 MB
  u16* YHL    = (u16*)(ws + (209ull << 20));    // 16 MB
  u16* PQHL   = (u16*)(ws + (225ull << 20));    // 16 MB -> total 241 MB

  const size_t WLO = 1048576;   // weight lo-plane offset (u16 elems)
  const size_t KLO = 524288;    // kv lo-plane offset
  const size_t A8  = 8 * MSZ;   // lo offset for 8-mat hi/lo buffers
  const unsigned FG = F_GSTRIDE;  // G-output epi flags (plain stores)

  // --- prologue: weight conv + x conv + neighbor lists + G gap zero ---
  WPtrs wp;
  wp.p[0] = W_lin;
  wp.p[1] = Wq_mp; wp.p[2] = Wq_mp + 65536; wp.p[3] = Wq_mp + 131072;
  wp.p[4] = Wk_mp; wp.p[5] = Wk_mp + 65536; wp.p[6] = Wk_mp + 131072;
  wp.p[7] = Wv_mp; wp.p[8] = Wv_mp + 65536; wp.p[9] = Wv_mp + 131072;
  wp.p[10] = Wk_att; wp.p[11] = Wv_att; wp.p[12] = Wq_att; wp.p[13] = Wo_att;
  wp.p[14] = W_proj; wp.p[15] = W_res;
  prologue_k<<<21040, 256, 0, stream>>>(wp, WSZ, x, XHL, A8, adj, CNT, IDX, GA, GB);

  // --- h = x @ W_lin + b_lin -> hi/lo planes ---
  gemm_k<1, 0u, F_BIAS | F_OUTHL, 0u, 0u><<<512, 512, 0, stream>>>(
      XHL, XHL, XHL, A8, WSZ, WSZ, WSZ, WLO,
      b_lin, nullptr, nullptr, mask, nullptr,
      bn_gamma, bn_beta, bn_mean, bn_var, nullptr,
      HHL, nullptr, nullptr, A8,
      nullptr, nullptr, nullptr, nullptr, CNT, IDX);

  // --- mp step 0: G0 = h @ W[0] (dense copy staging, gapped out) ---
  gemm_k<3, 0u, FG, FG, FG><<<1536, 512, 0, stream>>>(
      HHL, HHL, HHL, A8,
      WSZ + (size_t)1 * 65536, WSZ + (size_t)4 * 65536, WSZ + (size_t)7 * 65536, WLO,
      nullptr, nullptr, nullptr, mask, nullptr,
      bn_gamma, bn_beta, bn_mean, bn_var, nullptr,
      GA + 256, GA + 8 * GSTR + 256, GA + 16 * GSTR + 256, 0,
      nullptr, nullptr, nullptr, nullptr, CNT, IDX);

  // --- mp steps 1..5: fused-agg staging (A = silu(agg(G_prev)+b)), G ping-pong
  for (int s = 1; s < 6; s++) {
    int iw = s >> 1;            // weight index for this step
    int ib = (s - 1) >> 1;      // bias index of the fused agg (prev step)
    float* Gin = (s & 1) ? GA : GB;
    float* Gout = (s & 1) ? GB : GA;
    gemm_k<3, F_BIAS | F_SILU, FG, FG, FG><<<1536, 512, 0, stream>>>(
        nullptr, nullptr, nullptr, 0,
        WSZ + (size_t)(1 + iw) * 65536, WSZ + (size_t)(4 + iw) * 65536,
        WSZ + (size_t)(7 + iw) * 65536, WLO,
        nullptr, nullptr, nullptr, mask, nullptr,
        bn_gamma, bn_beta, bn_mean, bn_var, nullptr,
        Gout + 256, Gout + 8 * GSTR + 256, Gout + 16 * GSTR + 256, 0,
        Gin, bq_mp + ib * 256, bk_mp + ib * 256, bv_mp + ib * 256, CNT, IDX);
  }
  // G_5 lives in GB (s=5 wrote GB)

  // --- attention projections, fused final-agg staging + (pq | pk | pv) epis ---
  gemm_k<3, F_BIAS | F_SILU | F_MASKPOST,
         F_OUTHL, F_SILU | F_MASKPRE | F_TPLANES, F_MASKPOST | F_TPLANES>
      <<<1536, 512, 0, stream>>>(
      nullptr, nullptr, nullptr, 0,
      WSZ + (size_t)12 * 65536, WSZ + (size_t)10 * 65536, WSZ + (size_t)11 * 65536, WLO,
      nullptr, nullptr, nullptr, mask, nullptr,
      bn_gamma, bn_beta, bn_mean, bn_var, nullptr,
      PQHL, PKT, PVT, A8,
      GB, bq_mp + 512, bk_mp + 512, bv_mp + 512, CNT, IDX);

  // --- kv = pk^T pv ---
  kv_k<<<dim3(2, 2, 64), 256, 0, stream>>>(PKT, PVT, KVP);
  kv_conv_k<<<256, 256, 0, stream>>>(KVP, KVS);

  // --- attn = pq @ kv -> hi/lo ---
  gemm_k<1, 0u, F_BPERMAT | F_OUTHL, 0u, 0u><<<512, 512, 0, stream>>>(
      PQHL, PQHL, PQHL, A8, KVS, KVS, KVS, KLO,
      nullptr, nullptr, nullptr, mask, nullptr,
      bn_gamma, bn_beta, bn_mean, bn_var, nullptr,
      ATT, nullptr, nullptr, A8,
      nullptr, nullptr, nullptr, nullptr, CNT, IDX);

  // --- y = BN(attn @ Wo + x) -> hi/lo ---
  gemm_k<1, 0u, F_ADDX | F_BN | F_OUTHL, 0u, 0u><<<512, 512, 0, stream>>>(
      ATT, ATT, ATT, A8,
      WSZ + (size_t)13 * 65536, nullptr, nullptr, WLO,
      nullptr, nullptr, nullptr, mask, x,
      bn_gamma, bn_beta, bn_mean, bn_var, nullptr,
      YHL, nullptr, nullptr, A8,
      nullptr, nullptr, nullptr, nullptr, CNT, IDX);

  // --- out = (silu(y @ W_proj + b_proj) + x @ W_res + b_res) * mask, dual-K ---
  gemm_k<1, 0u, F_BIAS | F_MASKPOST, 0u, 0u, true><<<512, 512, 0, stream>>>(
      YHL, XHL, YHL, A8,
      WSZ + (size_t)14 * 65536, WSZ + (size_t)15 * 65536, nullptr, WLO,
      b_res, b_proj, nullptr, mask, nullptr,
      bn_gamma, bn_beta, bn_mean, bn_var, nullptr,
      d_out, nullptr, nullptr, 0,
      nullptr, nullptr, nullptr, nullptr, CNT, IDX);

  (void)in_sizes; (void)n_in; (void)out_size; (void)ws_size;
}

// Round 13
// 739.398 us; speedup vs baseline: 1.3407x; 1.0310x over previous
//
#include <hip/hip_runtime.h>
#include <stdint.h>

#define NB 8
#define NN 2048
#define NU 256
#define CAP 64
#define BNEPS 0.001f
#define GSTR ((size_t)(NN * NU + 256))   // G mat stride in floats (256-float zero gap BEFORE each mat)

typedef __attribute__((ext_vector_type(8))) short short8;
typedef __attribute__((ext_vector_type(4))) float floatx4;
typedef unsigned short u16;
typedef unsigned int u32;

__device__ __forceinline__ float bf2f(u16 u) {
  union { u32 i; float f; } c; c.i = ((u32)u) << 16; return c.f;
}
__device__ __forceinline__ u16 f2bf(float f) {
  union { float f; u32 i; } c; c.f = f;
  return (u16)((c.i + 0x7fffu + ((c.i >> 16) & 1u)) >> 16);
}
// bf16 hi/lo split: a = bf2f(h) + bf2f(l) + O(2^-18 |a|)
__device__ __forceinline__ void splitbf(float a, u16& h, u16& l) {
  h = f2bf(a);
  l = f2bf(a - bf2f(h));
}

enum : unsigned {
  F_BIAS = 2u, F_SILU = 4u, F_MASKPRE = 8u, F_MASKPOST = 16u,
  F_ADDX = 32u, F_BN = 64u, F_ADDT = 128u, F_BPERMAT = 512u,
  F_TPLANES = 1024u, F_OUTHL = 2048u, F_GSTRIDE = 8192u
};

#define TP_MAT 524288   // per-batch transposed plane: 256 cols x 2048 rows (u16)
#define TP_LO  4194304  // transposed lo plane offset (u16 elems)
#define MSZ ((size_t)NN * NU)
#define WFLO 196608     // WFZ lo-plane offset (3 mats * 65536 u16)

struct WPtrs { const float* p[16]; };

// ---------------------------------------------------------------------------
// Merged prologue: [0,512) weight conv, [512,4608) x conv, [4608,20992) nbr
// (pads idx rows to CAP with -1), [20992,21040) zero G mat gaps,
// [21040,21811) W-FUSION: WF_c = W_lin @ W_c0 (fp32), bF_c = b_lin @ W_c0.
// Algebraic fold: h@Wc0 = x@WF_c + bF_c  ->  h-GEMM dispatch eliminated
// (b_lin lives per-row in G0, summed cnt-times by the agg = reference).
// ---------------------------------------------------------------------------
__global__ __launch_bounds__(256) void prologue_k(
    WPtrs wp, u16* __restrict__ wdst,
    const float* __restrict__ x, u16* __restrict__ xdst, size_t xLo,
    const float* __restrict__ adj, int* __restrict__ cnt, int* __restrict__ idx,
    float* __restrict__ ga, float* __restrict__ gb,
    const float* __restrict__ blin, float* __restrict__ wf, float* __restrict__ bf)
{
  int bid = blockIdx.x;
  int tid = threadIdx.x;
  __shared__ int c0;
  __shared__ float arow[256];
  if (bid < 512) {
    // weight conversion: f32 [K=256][N=256] -> TWO bf16 swizzled-B^T planes
    int gid = bid * 256 + tid;  // 16 mats * 8192 chunks
    int mat = gid >> 13;
    int rem = gid & 8191;
    int kb = rem >> 10;
    int n = (rem >> 2) & 255;
    int slot = rem & 3;
    int qv = (slot - (n >> 1)) & 3;
    int k0 = kb * 32 + qv * 8;
    const float* W = wp.p[mat];
    u32 oh[4], ol[4];
#pragma unroll
    for (int t2 = 0; t2 < 4; t2++) {
      float f0 = W[(size_t)(k0 + 2 * t2) * 256 + n];
      float f1 = W[(size_t)(k0 + 2 * t2 + 1) * 256 + n];
      u16 h0, l0, h1, l1;
      splitbf(f0, h0, l0);
      splitbf(f1, h1, l1);
      oh[t2] = (u32)h0 | ((u32)h1 << 16);
      ol[t2] = (u32)l0 | ((u32)l1 << 16);
    }
    uint4 qh; qh.x = oh[0]; qh.y = oh[1]; qh.z = oh[2]; qh.w = oh[3];
    uint4 ql; ql.x = ol[0]; ql.y = ol[1]; ql.z = ol[2]; ql.w = ol[3];
    *(uint4*)(wdst + (size_t)gid * 8) = qh;
    *(uint4*)(wdst + 1048576 + (size_t)gid * 8) = ql;
  } else if (bid < 4608) {
    // x conversion: fp32 -> row-major hi/lo bf16 planes
    size_t i = ((size_t)(bid - 512) * 256 + tid) * 4;
    float4 v = *(const float4*)(x + i);
    u16 h0, l0, h1, l1, h2, l2, h3, l3;
    splitbf(v.x, h0, l0); splitbf(v.y, h1, l1);
    splitbf(v.z, h2, l2); splitbf(v.w, h3, l3);
    uint2 H; H.x = (u32)h0 | ((u32)h1 << 16); H.y = (u32)h2 | ((u32)h3 << 16);
    uint2 L; L.x = (u32)l0 | ((u32)l1 << 16); L.y = (u32)l2 | ((u32)l3 << 16);
    *(uint2*)(xdst + i) = H;
    *(uint2*)(xdst + xLo + i) = L;
  } else if (bid < 20992) {
    // neighbor-list build: one block per (b,m) row of adj; values exactly 0/1
    int row = bid - 4608;
    const float* base = adj + (size_t)row * NN;
    if (tid == 0) c0 = 0;
    __syncthreads();
#pragma unroll
    for (int j = 0; j < 8; j++) {
      int n = j * 256 + tid;  // coalesced
      if (base[n] != 0.f) {
        int p = atomicAdd(&c0, 1);
        if (p < CAP) idx[(size_t)row * CAP + p] = n;
      }
    }
    __syncthreads();
    int cc = (c0 < CAP ? c0 : CAP);
    for (int p = cc + tid; p < CAP; p += 256) idx[(size_t)row * CAP + p] = -1;
    if (tid == 0) cnt[row] = cc;
  } else if (bid < 21040) {
    // zero the 256-float gap before each of the 24 mats in GA and GB
    int g = bid - 20992;           // 0..47
    float* base = (g < 24 ? ga : gb) + (size_t)(g % 24) * GSTR;
    base[tid] = 0.f;
  } else {
    int idx2 = bid - 21040;        // 0..770
    if (idx2 < 768) {
      int c = idx2 >> 8;
      int r = idx2 & 255;
      const float* Wc = wp.p[1 + 3 * c];   // Wq_mp / Wk_mp / Wv_mp (mat 0)
      arow[tid] = wp.p[0][r * 256 + tid];  // W_lin row r
      __syncthreads();
      float acc = 0.f;
      for (int k = 0; k < 256; k++) acc += arow[k] * Wc[k * 256 + tid];
      wf[(size_t)c * 65536 + (size_t)r * 256 + tid] = acc;
    } else {
      int c = idx2 - 768;
      const float* Wc = wp.p[1 + 3 * c];
      arow[tid] = blin[tid];
      __syncthreads();
      float acc = 0.f;
      for (int k = 0; k < 256; k++) acc += arow[k] * Wc[k * 256 + tid];
      bf[c * 256 + tid] = acc;
    }
  }
}

// Convert the 3 fused WF mats (fp32) -> swizzled hi/lo planes in WFZ
// (hi: mat m at m*65536; lo at +WFLO).
__global__ __launch_bounds__(256) void convf_k(
    const float* __restrict__ wf, u16* __restrict__ wfz)
{
  int gid = blockIdx.x * 256 + threadIdx.x;  // 96*256 = 3*8192
  int m = gid >> 13;
  int rem = gid & 8191;
  int kb = rem >> 10;
  int n = (rem >> 2) & 255;
  int slot = rem & 3;
  int qv = (slot - (n >> 1)) & 3;
  int k0 = kb * 32 + qv * 8;
  const float* W = wf + (size_t)m * 65536;
  u32 oh[4], ol[4];
#pragma unroll
  for (int t2 = 0; t2 < 4; t2++) {
    float f0 = W[(size_t)(k0 + 2 * t2) * 256 + n];
    float f1 = W[(size_t)(k0 + 2 * t2 + 1) * 256 + n];
    u16 h0, l0, h1, l1;
    splitbf(f0, h0, l0);
    splitbf(f1, h1, l1);
    oh[t2] = (u32)h0 | ((u32)h1 << 16);
    ol[t2] = (u32)l0 | ((u32)l1 << 16);
  }
  uint4 qh; qh.x = oh[0]; qh.y = oh[1]; qh.z = oh[2]; qh.w = oh[3];
  uint4 ql; ql.x = ol[0]; ql.y = ol[1]; ql.z = ol[2]; ql.w = ol[3];
  *(uint4*)(wfz + (size_t)gid * 8) = qh;
  *(uint4*)(wfz + WFLO + (size_t)gid * 8) = ql;
}

// ---------------------------------------------------------------------------
// Per-chain epilogue (compile-time flags). Wave layout: 32 rows x 32 cols.
// ---------------------------------------------------------------------------
template <unsigned F>
__device__ __forceinline__ void gemm_epi(
    floatx4 (&acc)[2][2], int b, int bm, int w, int m16, int q,
    const float* __restrict__ bias, const float* __restrict__ mask,
    const float* __restrict__ xf32,
    const float* __restrict__ gma, const float* __restrict__ bta,
    const float* __restrict__ bmu, const float* __restrict__ bvr,
    const float* __restrict__ addt, void* __restrict__ outp, size_t oLo)
{
#pragma unroll
  for (int mt = 0; mt < 2; mt++) {
    if (F & F_TPLANES) {
      u16* oh = (u16*)outp + (size_t)b * TP_MAT;
      u16* ol = oh + TP_LO;
      int gr0 = bm + mt * 16 + q * 4;
#pragma unroll
      for (int nt = 0; nt < 2; nt++) {
        int col = w * 32 + nt * 16 + m16;
        u16 hh[4], ll[4];
#pragma unroll
        for (int r = 0; r < 4; r++) {
          float t2 = acc[mt][nt][r];
          float mv = mask[b * NN + gr0 + r];
          if (F & F_MASKPRE) t2 *= mv;
          if (F & F_SILU) t2 = t2 / (1.f + __expf(-t2));
          if (F & F_MASKPOST) t2 *= mv;
          splitbf(t2, hh[r], ll[r]);
        }
        uint2 H2, L2v;
        H2.x = (u32)hh[0] | ((u32)hh[1] << 16);
        H2.y = (u32)hh[2] | ((u32)hh[3] << 16);
        L2v.x = (u32)ll[0] | ((u32)ll[1] << 16);
        L2v.y = (u32)ll[2] | ((u32)ll[3] << 16);
        *(uint2*)(oh + (size_t)col * 2048 + gr0) = H2;
        *(uint2*)(ol + (size_t)col * 2048 + gr0) = L2v;
      }
    } else {
#pragma unroll
      for (int r = 0; r < 4; r++) {
        int gr = bm + mt * 16 + q * 4 + r;
        float mval = 1.f;
        if (F & (F_MASKPRE | F_MASKPOST)) mval = mask[b * NN + gr];
#pragma unroll
        for (int nt = 0; nt < 2; nt++) {
          int col = w * 32 + nt * 16 + m16;
          float t2 = acc[mt][nt][r];
          if (F & F_BIAS) t2 += bias[col];
          if (F & F_MASKPRE) t2 *= mval;
          if (F & F_SILU) t2 = t2 / (1.f + __expf(-t2));
          if (F & F_ADDX) t2 += xf32[((size_t)b * NN + gr) * NU + col];
          if (F & F_BN) t2 = gma[col] * (t2 - bmu[col]) * rsqrtf(bvr[col] + BNEPS) + bta[col];
          if (F & F_ADDT) t2 += addt[((size_t)b * NN + gr) * NU + col];
          if (F & F_MASKPOST) t2 *= mval;
          size_t o;
          if (F & F_GSTRIDE) o = (size_t)b * GSTR + (size_t)gr * NU + col;
          else o = ((size_t)b * NN + gr) * NU + col;
          if (F & F_OUTHL) {
            u16 h0, l0;
            splitbf(t2, h0, l0);
            ((u16*)outp)[o] = h0;
            ((u16*)outp)[o + oLo] = l0;
          } else {
            ((float*)outp)[o] = t2;
          }
        }
      }
    }
  }
}

// ---------------------------------------------------------------------------
// Dense GEMM, fp32-emulated via bf16 hi/lo 3-term MFMA (R2 config: 32x256
// tile, 33.8 KB LDS, branchy exact gather — measured pattern ceiling).
// ---------------------------------------------------------------------------
template <int NG, unsigned SF, unsigned F0, unsigned F1, unsigned F2, bool DK = false>
__global__ __launch_bounds__(512, 8) void gemm_k(
    const u16* __restrict__ A0, const u16* __restrict__ A1, const u16* __restrict__ A2,
    size_t aLo,
    const u16* __restrict__ W0, const u16* __restrict__ W1, const u16* __restrict__ W2,
    size_t wLo,
    const float* __restrict__ b0, const float* __restrict__ b1, const float* __restrict__ b2,
    const float* __restrict__ mask,
    const float* __restrict__ xf32,
    const float* __restrict__ gma, const float* __restrict__ bta,
    const float* __restrict__ bmu, const float* __restrict__ bvr,
    const float* __restrict__ addt,
    void* __restrict__ o0, void* __restrict__ o1, void* __restrict__ o2,
    size_t oLo,
    const float* __restrict__ gsrc,
    const float* __restrict__ sb0, const float* __restrict__ sb1, const float* __restrict__ sb2,
    const int* __restrict__ ncnt, const int* __restrict__ nidx)
{
  const int tid = threadIdx.x;
  const int id = blockIdx.x;
  const int xcd = id & 7;
  const int t = id >> 3;
  const int chain = (NG == 1) ? 0 : (t >> 6);
  const int xt = (NG == 1) ? t : (t & 63);
  const int b = xcd;
  const int bm = xt * 32;

  __shared__ alignas(16) u16 Ah[32 * 264];
  __shared__ alignas(16) u16 Al[32 * 264];

  const u16* Wsel = (chain == 0) ? W0 : (chain == 1 ? W1 : W2);
  if (F0 & F_BPERMAT) Wsel = W0 + (size_t)b * 65536;
  const u16* Whi = Wsel;
  const u16* Wlo = Whi + wLo;

  const int lane = tid & 63;
  const int w = tid >> 6;

  if constexpr (SF != 0u) {
    const float* __restrict__ gm = gsrc + (size_t)(chain * 8 + b) * GSTR + 256;
    const float* sb = (chain == 0) ? sb0 : (chain == 1 ? sb1 : sb2);
    const int c = lane * 4;
    float4 bb = *(const float4*)(sb + c);
    const int r0 = w * 4;
    int cnts[4];
    const int* ips[4];
    float4 av[4];
    int rowids[4];
#pragma unroll
    for (int i = 0; i < 4; i++) {
      rowids[i] = b * NN + bm + r0 + i;
      cnts[i] = ncnt[rowids[i]];
      ips[i] = nidx + (size_t)rowids[i] * CAP;
      av[i].x = av[i].y = av[i].z = av[i].w = 0.f;
    }
    int maxc = cnts[0];
    maxc = cnts[1] > maxc ? cnts[1] : maxc;
    maxc = cnts[2] > maxc ? cnts[2] : maxc;
    maxc = cnts[3] > maxc ? cnts[3] : maxc;
    for (int e = 0; e + 4 <= maxc; e += 4) {
#pragma unroll
      for (int i = 0; i < 4; i++) {
        if (e + 4 <= cnts[i]) {
          int4 i4 = *(const int4*)(ips[i] + e);
          float4 v0 = *(const float4*)(gm + ((size_t)i4.x << 8) + c);
          float4 v1 = *(const float4*)(gm + ((size_t)i4.y << 8) + c);
          float4 v2 = *(const float4*)(gm + ((size_t)i4.z << 8) + c);
          float4 v3 = *(const float4*)(gm + ((size_t)i4.w << 8) + c);
          av[i].x += v0.x + v1.x + v2.x + v3.x;
          av[i].y += v0.y + v1.y + v2.y + v3.y;
          av[i].z += v0.z + v1.z + v2.z + v3.z;
          av[i].w += v0.w + v1.w + v2.w + v3.w;
        }
      }
    }
#pragma unroll
    for (int i = 0; i < 4; i++) {
      for (int e = cnts[i] & ~3; e < cnts[i]; e++) {
        float4 v = *(const float4*)(gm + ((size_t)ips[i][e] << 8) + c);
        av[i].x += v.x; av[i].y += v.y; av[i].z += v.z; av[i].w += v.w;
      }
    }
#pragma unroll
    for (int i = 0; i < 4; i++) {
      float ov[4] = {av[i].x + bb.x, av[i].y + bb.y, av[i].z + bb.z, av[i].w + bb.w};
      float mv = (SF & F_MASKPOST) ? mask[rowids[i]] : 1.f;
      u16 hh[4], ll[4];
#pragma unroll
      for (int j = 0; j < 4; j++) {
        float t2 = ov[j];
        if (SF & F_SILU) t2 = t2 / (1.f + __expf(-t2));
        if (SF & F_MASKPOST) t2 *= mv;
        splitbf(t2, hh[j], ll[j]);
      }
      uint2 H; H.x = (u32)hh[0] | ((u32)hh[1] << 16); H.y = (u32)hh[2] | ((u32)hh[3] << 16);
      uint2 L; L.x = (u32)ll[0] | ((u32)ll[1] << 16); L.y = (u32)ll[2] | ((u32)ll[3] << 16);
      *(uint2*)&Ah[(r0 + i) * 264 + c] = H;
      *(uint2*)&Al[(r0 + i) * 264 + c] = L;
    }
  } else {
    const u16* Abase = (chain == 0) ? A0 : (chain == 1 ? A1 : A2);
    const u16* Ahp = Abase + (size_t)b * MSZ;
    const u16* Alp = Ahp + aLo;
    {
      int s = tid;
      int r = s >> 4;
      int c = (s & 15) << 4;
      size_t ao = (size_t)(bm + r) * 256 + c;
      *(uint4*)&Ah[r * 264 + c] = *(const uint4*)(Ahp + ao);
      *(uint4*)&Ah[r * 264 + c + 8] = *(const uint4*)(Ahp + ao + 8);
      *(uint4*)&Al[r * 264 + c] = *(const uint4*)(Alp + ao);
      *(uint4*)&Al[r * 264 + c + 8] = *(const uint4*)(Alp + ao + 8);
    }
  }
  __syncthreads();

  const int m16 = lane & 15;
  const int q = lane >> 4;

  floatx4 acc[2][2];
#pragma unroll
  for (int i = 0; i < 2; i++)
#pragma unroll
    for (int j = 0; j < 2; j++) acc[i][j] = (floatx4){0.f, 0.f, 0.f, 0.f};

#pragma unroll
  for (int kk = 0; kk < 8; kk++) {
    short8 bh[2], bl2[2];
#pragma unroll
    for (int nt = 0; nt < 2; nt++) {
      int n = w * 32 + nt * 16 + m16;
      size_t off = (size_t)kk * 8192 + (size_t)n * 32 + (size_t)(((q + (n >> 1)) & 3) * 8);
      bh[nt] = *(const short8*)(Whi + off);
      bl2[nt] = *(const short8*)(Wlo + off);
    }
#pragma unroll
    for (int mt = 0; mt < 2; mt++) {
      int row = mt * 16 + m16;
      short8 ah = *(const short8*)&Ah[row * 264 + kk * 32 + q * 8];
      short8 al2 = *(const short8*)&Al[row * 264 + kk * 32 + q * 8];
#pragma unroll
      for (int nt = 0; nt < 2; nt++) {
        acc[mt][nt] = __builtin_amdgcn_mfma_f32_16x16x32_bf16(ah, bh[nt], acc[mt][nt], 0, 0, 0);
        acc[mt][nt] = __builtin_amdgcn_mfma_f32_16x16x32_bf16(al2, bh[nt], acc[mt][nt], 0, 0, 0);
        acc[mt][nt] = __builtin_amdgcn_mfma_f32_16x16x32_bf16(ah, bl2[nt], acc[mt][nt], 0, 0, 0);
      }
    }
  }

  if constexpr (DK) {
#pragma unroll
    for (int mt = 0; mt < 2; mt++)
#pragma unroll
      for (int nt = 0; nt < 2; nt++) {
        int col = w * 32 + nt * 16 + m16;
        float bp = b1[col];
#pragma unroll
        for (int r = 0; r < 4; r++) {
          float t2 = acc[mt][nt][r] + bp;
          acc[mt][nt][r] = t2 / (1.f + __expf(-t2));
        }
      }
    __syncthreads();
    {
      const u16* Ahp = A1 + (size_t)b * MSZ;
      const u16* Alp = Ahp + aLo;
      int s = tid;
      int r = s >> 4;
      int c = (s & 15) << 4;
      size_t ao = (size_t)(bm + r) * 256 + c;
      *(uint4*)&Ah[r * 264 + c] = *(const uint4*)(Ahp + ao);
      *(uint4*)&Ah[r * 264 + c + 8] = *(const uint4*)(Ahp + ao + 8);
      *(uint4*)&Al[r * 264 + c] = *(const uint4*)(Alp + ao);
      *(uint4*)&Al[r * 264 + c + 8] = *(const uint4*)(Alp + ao + 8);
    }
    __syncthreads();
    const u16* W1h = W1;
    const u16* W1l = W1 + wLo;
#pragma unroll
    for (int kk = 0; kk < 8; kk++) {
      short8 bh[2], bl2[2];
#pragma unroll
      for (int nt = 0; nt < 2; nt++) {
        int n = w * 32 + nt * 16 + m16;
        size_t off = (size_t)kk * 8192 + (size_t)n * 32 + (size_t)(((q + (n >> 1)) & 3) * 8);
        bh[nt] = *(const short8*)(W1h + off);
        bl2[nt] = *(const short8*)(W1l + off);
      }
#pragma unroll
      for (int mt = 0; mt < 2; mt++) {
        int row = mt * 16 + m16;
        short8 ah = *(const short8*)&Ah[row * 264 + kk * 32 + q * 8];
        short8 al2 = *(const short8*)&Al[row * 264 + kk * 32 + q * 8];
#pragma unroll
        for (int nt = 0; nt < 2; nt++) {
          acc[mt][nt] = __builtin_amdgcn_mfma_f32_16x16x32_bf16(ah, bh[nt], acc[mt][nt], 0, 0, 0);
          acc[mt][nt] = __builtin_amdgcn_mfma_f32_16x16x32_bf16(al2, bh[nt], acc[mt][nt], 0, 0, 0);
          acc[mt][nt] = __builtin_amdgcn_mfma_f32_16x16x32_bf16(ah, bl2[nt], acc[mt][nt], 0, 0, 0);
        }
      }
    }
  }

  if (NG == 1 || chain == 0)
    gemm_epi<F0>(acc, b, bm, w, m16, q, b0, mask, xf32, gma, bta, bmu, bvr, addt, o0, oLo);
  else if (chain == 1)
    gemm_epi<F1>(acc, b, bm, w, m16, q, b1, mask, xf32, gma, bta, bmu, bvr, addt, o1, oLo);
  else
    gemm_epi<F2>(acc, b, bm, w, m16, q, b2, mask, xf32, gma, bta, bmu, bvr, addt, o2, oLo);
}

// ---------------------------------------------------------------------------
// kv[d][e] = sum_n pk[n][d] * pv[n][e], split-K=8 partials.
// ---------------------------------------------------------------------------
__global__ __launch_bounds__(256, 2) void kv_k(
    const u16* __restrict__ pkT, const u16* __restrict__ pvT, float* __restrict__ part)
{
  int et = blockIdx.x * 128;
  int dt = blockIdx.y * 128;
  int z = blockIdx.z;
  int b = z & 7;
  int p = z >> 3;
  int tid = threadIdx.x;
  int lane = tid & 63, w = tid >> 6;
  int m16 = lane & 15, q = lane >> 4;

  const u16* pkh = pkT + (size_t)b * TP_MAT;
  const u16* pkl = pkh + TP_LO;
  const u16* pvh = pvT + (size_t)b * TP_MAT;
  const u16* pvl = pvh + TP_LO;

  int d_base = dt + (w >> 1) * 64 + m16;
  int e_base = et + (w & 1) * 64 + m16;

  floatx4 acc[4][4];
#pragma unroll
  for (int i = 0; i < 4; i++)
#pragma unroll
    for (int j = 0; j < 4; j++) acc[i][j] = (floatx4){0.f, 0.f, 0.f, 0.f};

#pragma unroll
  for (int kt = 0; kt < 8; kt++) {
    int kc = p * 256 + kt * 32 + q * 8;
    short8 ah[4], al[4], bh[4], bl[4];
#pragma unroll
    for (int mt = 0; mt < 4; mt++) {
      size_t o = (size_t)(d_base + mt * 16) * 2048 + kc;
      ah[mt] = *(const short8*)(pkh + o);
      al[mt] = *(const short8*)(pkl + o);
    }
#pragma unroll
    for (int nt = 0; nt < 4; nt++) {
      size_t o = (size_t)(e_base + nt * 16) * 2048 + kc;
      bh[nt] = *(const short8*)(pvh + o);
      bl[nt] = *(const short8*)(pvl + o);
    }
#pragma unroll
    for (int mt = 0; mt < 4; mt++)
#pragma unroll
      for (int nt = 0; nt < 4; nt++) {
        acc[mt][nt] = __builtin_amdgcn_mfma_f32_16x16x32_bf16(ah[mt], bh[nt], acc[mt][nt], 0, 0, 0);
        acc[mt][nt] = __builtin_amdgcn_mfma_f32_16x16x32_bf16(al[mt], bh[nt], acc[mt][nt], 0, 0, 0);
        acc[mt][nt] = __builtin_amdgcn_mfma_f32_16x16x32_bf16(ah[mt], bl[nt], acc[mt][nt], 0, 0, 0);
      }
  }

#pragma unroll
  for (int mt = 0; mt < 4; mt++)
#pragma unroll
    for (int r = 0; r < 4; r++) {
      int d = dt + (w >> 1) * 64 + mt * 16 + q * 4 + r;
#pragma unroll
      for (int nt = 0; nt < 4; nt++) {
        int e = et + (w & 1) * 64 + nt * 16 + m16;
        part[(size_t)z * 65536 + (size_t)d * 256 + e] = acc[mt][nt][r];
      }
    }
}

// KVO[b] = (sum_p part[p][b]) @ Wo (fp32). Fold (pq@kv)@Wo = pq@(kv@Wo):
// kills the 2048-row attn GEMM and the 16 MB ATT round-trip.
__global__ __launch_bounds__(256) void kvo_k(
    const float* __restrict__ part, const float* __restrict__ Wo,
    float* __restrict__ kvo)
{
  __shared__ float krow[256];
  int bid = blockIdx.x;      // 2048 = 8 * 256
  int b = bid >> 8;
  int d = bid & 255;
  int tid = threadIdx.x;
  float s = 0.f;
  size_t base = (size_t)b * 65536 + (size_t)d * 256 + tid;
#pragma unroll
  for (int pp = 0; pp < 8; pp++) s += part[base + (size_t)pp * 524288];
  krow[tid] = s;
  __syncthreads();
  float acc = 0.f;
  for (int e = 0; e < 256; e++) acc += krow[e] * Wo[(size_t)e * 256 + tid];
  kvo[(size_t)b * 65536 + (size_t)d * 256 + tid] = acc;
}

// Convert KVO (8 fp32 mats) -> swizzled per-b bf16 hi/lo weight planes.
__global__ __launch_bounds__(256) void kvoconv_k(
    const float* __restrict__ kvo, u16* __restrict__ dst)
{
  int gid = blockIdx.x * 256 + threadIdx.x;  // 8 * 8192 = 65536
  int b = gid >> 13;
  int rem = gid & 8191;
  int kb = rem >> 10;
  int e = (rem >> 2) & 255;
  int slot = rem & 3;
  int qv = (slot - (e >> 1)) & 3;
  int d0 = kb * 32 + qv * 8;
  const float* src = kvo + (size_t)b * 65536 + (size_t)d0 * 256 + e;
  u32 oh[4], ol[4];
#pragma unroll
  for (int t2 = 0; t2 < 4; t2++) {
    float s0 = src[t2 * 512];
    float s1 = src[t2 * 512 + 256];
    u16 h0, l0, h1, l1;
    splitbf(s0, h0, l0);
    splitbf(s1, h1, l1);
    oh[t2] = (u32)h0 | ((u32)h1 << 16);
    ol[t2] = (u32)l0 | ((u32)l1 << 16);
  }
  uint4 qh; qh.x = oh[0]; qh.y = oh[1]; qh.z = oh[2]; qh.w = oh[3];
  uint4 ql; ql.x = ol[0]; ql.y = ol[1]; ql.z = ol[2]; ql.w = ol[3];
  *(uint4*)(dst + (size_t)gid * 8) = qh;
  *(uint4*)(dst + 524288 + (size_t)gid * 8) = ql;
}

// ---------------------------------------------------------------------------
extern "C" void kernel_launch(void* const* d_in, const int* in_sizes, int n_in,
                              void* d_out, int out_size, void* d_ws, size_t ws_size,
                              hipStream_t stream)
{
  const float* x = (const float*)d_in[0];
  const float* adj = (const float*)d_in[1];
  const float* mask = (const float*)d_in[2];
  const float* W_lin = (const float*)d_in[3];
  const float* b_lin = (const float*)d_in[4];
  const float* Wq_mp = (const float*)d_in[5];
  const float* bq_mp = (const float*)d_in[6];
  const float* Wk_mp = (const float*)d_in[7];
  const float* bk_mp = (const float*)d_in[8];
  const float* Wv_mp = (const float*)d_in[9];
  const float* bv_mp = (const float*)d_in[10];
  const float* Wk_att = (const float*)d_in[11];
  const float* Wv_att = (const float*)d_in[12];
  const float* Wq_att = (const float*)d_in[13];
  const float* Wo_att = (const float*)d_in[14];
  const float* bn_gamma = (const float*)d_in[15];
  const float* bn_beta = (const float*)d_in[16];
  const float* bn_mean = (const float*)d_in[17];
  const float* bn_var = (const float*)d_in[18];
  const float* W_proj = (const float*)d_in[19];
  const float* b_proj = (const float*)d_in[20];
  const float* W_res = (const float*)d_in[21];
  const float* b_res = (const float*)d_in[22];

  char* ws = (char*)d_ws;
  int* CNT    = (int*)(ws + 0);                 // 64 KB
  int* IDX    = (int*)(ws + (1ull << 20));      // 4 MB
  u16* WSZ    = (u16*)(ws + (5ull << 20));      // 4 MB (bf16 hi 2MB + lo 2MB)
  u16* KVS    = (u16*)(ws + (9ull << 20));      // 2 MB (KVO swizzled planes)
  float* KVP  = (float*)(ws + (11ull << 20));   // 16 MB (kv split-K partials)
  u16* XHL    = (u16*)(ws + (27ull << 20));     // 16 MB (8 hi + 8 lo)
  float* WF   = (float*)(ws + (43ull << 20));   // 768 KB (3 fused W mats fp32)
  float* BF   = (float*)(ws + (44ull << 20));   // 3 KB (3 fused bias rows)
  float* KVO  = (float*)(ws + (45ull << 20));   // 2 MB (kv@Wo fp32)
  u16* WFZ    = (u16*)(ws + (48ull << 20));     // 768 KB (WF swizzled hi+lo)
  float* GA   = (float*)(ws + (59ull << 20));   // 50.4 MB fp32 (24 gapped mats)
  float* GB   = (float*)(ws + (110ull << 20));  // 50.4 MB fp32 (ping-pong)
  u16* PKT    = (u16*)(ws + (161ull << 20));    // 16 MB
  u16* PVT    = (u16*)(ws + (177ull << 20));    // 16 MB
  u16* YHL    = (u16*)(ws + (209ull << 20));    // 16 MB
  u16* PQHL   = (u16*)(ws + (225ull << 20));    // 16 MB -> total 241 MB

  const size_t WLO = 1048576;   // weight lo-plane offset (u16 elems)
  const size_t KLO = 524288;    // kv lo-plane offset
  const size_t A8  = 8 * MSZ;   // lo offset for 8-mat hi/lo buffers
  const unsigned FG = F_GSTRIDE;

  // --- prologue: conv + x conv + nbr + G gaps + W-fusion (one launch) ---
  WPtrs wp;
  wp.p[0] = W_lin;
  wp.p[1] = Wq_mp; wp.p[2] = Wq_mp + 65536; wp.p[3] = Wq_mp + 131072;
  wp.p[4] = Wk_mp; wp.p[5] = Wk_mp + 65536; wp.p[6] = Wk_mp + 131072;
  wp.p[7] = Wv_mp; wp.p[8] = Wv_mp + 65536; wp.p[9] = Wv_mp + 131072;
  wp.p[10] = Wk_att; wp.p[11] = Wv_att; wp.p[12] = Wq_att; wp.p[13] = Wo_att;
  wp.p[14] = W_proj; wp.p[15] = W_res;
  prologue_k<<<21811, 256, 0, stream>>>(wp, WSZ, x, XHL, A8, adj, CNT, IDX,
                                        GA, GB, b_lin, WF, BF);
  convf_k<<<96, 256, 0, stream>>>(WF, WFZ);

  // --- mp step 0 (h-GEMM folded): G0_c = x @ WF_c + bF_c, from XHL ---
  gemm_k<3, 0u, FG | F_BIAS, FG | F_BIAS, FG | F_BIAS><<<1536, 512, 0, stream>>>(
      XHL, XHL, XHL, A8,
      WFZ, WFZ + 65536, WFZ + 131072, WFLO,
      BF, BF + 256, BF + 512, mask, nullptr,
      bn_gamma, bn_beta, bn_mean, bn_var, nullptr,
      GA + 256, GA + 8 * GSTR + 256, GA + 16 * GSTR + 256, 0,
      nullptr, nullptr, nullptr, nullptr, CNT, IDX);

  // --- mp steps 1..5: fused-agg staging (A = silu(agg(G_prev)+b)) ---
  for (int s = 1; s < 6; s++) {
    int iw = s >> 1;
    int ib = (s - 1) >> 1;
    float* Gin = (s & 1) ? GA : GB;
    float* Gout = (s & 1) ? GB : GA;
    gemm_k<3, F_BIAS | F_SILU, FG, FG, FG><<<1536, 512, 0, stream>>>(
        nullptr, nullptr, nullptr, 0,
        WSZ + (size_t)(1 + iw) * 65536, WSZ + (size_t)(4 + iw) * 65536,
        WSZ + (size_t)(7 + iw) * 65536, WLO,
        nullptr, nullptr, nullptr, mask, nullptr,
        bn_gamma, bn_beta, bn_mean, bn_var, nullptr,
        Gout + 256, Gout + 8 * GSTR + 256, Gout + 16 * GSTR + 256, 0,
        Gin, bq_mp + ib * 256, bk_mp + ib * 256, bv_mp + ib * 256, CNT, IDX);
  }

  // --- attention projections, fused final-agg staging ---
  gemm_k<3, F_BIAS | F_SILU | F_MASKPOST,
         F_OUTHL, F_SILU | F_MASKPRE | F_TPLANES, F_MASKPOST | F_TPLANES>
      <<<1536, 512, 0, stream>>>(
      nullptr, nullptr, nullptr, 0,
      WSZ + (size_t)12 * 65536, WSZ + (size_t)10 * 65536, WSZ + (size_t)11 * 65536, WLO,
      nullptr, nullptr, nullptr, mask, nullptr,
      bn_gamma, bn_beta, bn_mean, bn_var, nullptr,
      PQHL, PKT, PVT, A8,
      GB, bq_mp + 512, bk_mp + 512, bv_mp + 512, CNT, IDX);

  // --- kv = pk^T pv ; KVO = kv @ Wo ; swizzle ---
  kv_k<<<dim3(2, 2, 64), 256, 0, stream>>>(PKT, PVT, KVP);
  kvo_k<<<2048, 256, 0, stream>>>(KVP, Wo_att, KVO);
  kvoconv_k<<<256, 256, 0, stream>>>(KVO, KVS);

  // --- y = BN(pq @ KVO + x) -> hi/lo (attn GEMM folded away) ---
  gemm_k<1, 0u, F_BPERMAT | F_ADDX | F_BN | F_OUTHL, 0u, 0u><<<512, 512, 0, stream>>>(
      PQHL, PQHL, PQHL, A8, KVS, KVS, KVS, KLO,
      nullptr, nullptr, nullptr, mask, x,
      bn_gamma, bn_beta, bn_mean, bn_var, nullptr,
      YHL, nullptr, nullptr, A8,
      nullptr, nullptr, nullptr, nullptr, CNT, IDX);

  // --- out = (silu(y @ W_proj + b_proj) + x @ W_res + b_res) * mask ---
  gemm_k<1, 0u, F_BIAS | F_MASKPOST, 0u, 0u, true><<<512, 512, 0, stream>>>(
      YHL, XHL, YHL, A8,
      WSZ + (size_t)14 * 65536, WSZ + (size_t)15 * 65536, nullptr, WLO,
      b_res, b_proj, nullptr, mask, nullptr,
      bn_gamma, bn_beta, bn_mean, bn_var, nullptr,
      d_out, nullptr, nullptr, 0,
      nullptr, nullptr, nullptr, nullptr, CNT, IDX);

  (void)in_sizes; (void)n_in; (void)out_size; (void)ws_size;
}